// Round 5
// baseline (481.929 us; speedup 1.0000x reference)
//
#include <hip/hip_runtime.h>
#include <math.h>

#define NN 100000
#define NP 100032              // padded to 64-row multiple (1563 * 64)
#define HIDC 128
#define OUTC 40
#define NBUCK ((NN + 511) >> 9)   // 196 buckets of 512 dst nodes
#define PT_TILE 4096
#define BCAP 18368             // fixed per-bucket pairs capacity (mean 16327, sigma~127)

typedef __attribute__((ext_vector_type(2))) float floatx2;
typedef __attribute__((ext_vector_type(4))) float floatx4;
typedef __attribute__((ext_vector_type(8))) short short8;
typedef __attribute__((ext_vector_type(4))) unsigned uintx4;

// bf16 helpers (RN) -------------------------------------------------------
__device__ __forceinline__ unsigned pack_bf16x2(float a, float b) {
  unsigned ua = __float_as_uint(a), ub = __float_as_uint(b);
  ua = ua + 0x7fff + ((ua >> 16) & 1);
  ub = ub + 0x7fff + ((ub >> 16) & 1);
  return (ua >> 16) | (ub & 0xffff0000u);
}
__device__ __forceinline__ unsigned short bf16r(float x) {
  unsigned u = __float_as_uint(x);
  u = u + 0x7fff + ((u >> 16) & 1);
  return (unsigned short)(u >> 16);
}

// ---------------- graph prep (bucket-based, fixed-capacity runs) ----------------
// LDS-staged counting sort (R4): regs->LDS-sorted->LINEAR global write.

__global__ __launch_bounds__(512) void partition_kernel(
    const int* __restrict__ src, const int* __restrict__ dst,
    int* __restrict__ bcur, unsigned* __restrict__ pairs, int E) {
  __shared__ int hist[256];
  __shared__ int lcur[256];
  __shared__ int startl[256];   // local exclusive prefix (then searched)
  __shared__ int gofs[256];     // global_base[b] - startl[b]
  __shared__ unsigned lbuf[PT_TILE];  // 16 KB
  int t = threadIdx.x;
  if (t < 256) { hist[t] = 0; lcur[t] = 0; }
  __syncthreads();
  int e0 = blockIdx.x * PT_TILE;
  int ec = E - e0; if (ec > PT_TILE) ec = PT_TILE;

  // pass 1: load edges to regs + bucket histogram
  int dr[8], sr[8];
#pragma unroll
  for (int k = 0; k < 8; k++) {
    int i = t + (k << 9);
    if (i < ec) {
      int d = dst[e0 + i];
      dr[k] = d; sr[k] = src[e0 + i];
      atomicAdd(&hist[d >> 9], 1);
    }
  }
  __syncthreads();

  // inclusive scan of hist over 256 (first 256 threads), then exclusive + base
  int h = (t < 256) ? hist[t] : 0;
  if (t < 256) startl[t] = h;
  __syncthreads();
  for (int off = 1; off < 256; off <<= 1) {
    int u = (t < 256 && t >= off) ? startl[t - off] : 0;
    __syncthreads();
    if (t < 256) startl[t] += u;
    __syncthreads();
  }
  if (t < 256) {
    int st = startl[t] - h;          // exclusive start
    int gb = (h > 0) ? atomicAdd(&bcur[t], h) : 0;
    gofs[t] = gb - st;
    startl[t] = st;
  }
  __syncthreads();

  // pass 2: scatter into LDS (random LDS is cheap)
#pragma unroll
  for (int k = 0; k < 8; k++) {
    int i = t + (k << 9);
    if (i < ec) {
      int d = dr[k];
      int b = d >> 9;
      int q = atomicAdd(&lcur[b], 1);
      lbuf[startl[b] + q] = ((unsigned)(d & 511) << 17) | (unsigned)sr[k];
    }
  }
  __syncthreads();

  // pass 3: linear coalesced write-out; binary search owning bucket
  for (int pos = t; pos < ec; pos += 512) {
    int lo = 0, hi = 255;
    while (lo < hi) {
      int mid = (lo + hi + 1) >> 1;
      if (startl[mid] <= pos) lo = mid; else hi = mid - 1;
    }
    pairs[gofs[lo] + pos] = lbuf[pos];
  }
}

// per-bucket: LDS hist(512)+scan -> dinv/cur; degree counting-sort emits
// sorted metadata (sbeg/send/sdinv/sdn); then csr scatter WITH LDS CURSORS,
// one block per bucket -> all csr writes for a bucket's 73KB window come from
// one CU/XCD and coalesce in that XCD's L2 (R2 lesson: splitting the scatter
// across XCDs caused 10x write amplification on the non-coherent L2s).
__global__ __launch_bounds__(1024) void bucket_fill_kernel(
    const unsigned* __restrict__ pairs, const int* __restrict__ bcur,
    float* __restrict__ dinv, int* __restrict__ csr,
    int* __restrict__ sbeg, int* __restrict__ send,
    float* __restrict__ sdinv, int* __restrict__ sdn, int N) {
  int b = blockIdx.x;
  int d0 = b << 9;
  int nd = N - d0; if (nd > 512) nd = 512;
  __shared__ int hist[512];
  __shared__ int cur[512];
  __shared__ int sums[512];
  int t = threadIdx.x;
  if (t < 512) hist[t] = 0;
  __syncthreads();
  int rbeg = b * BCAP, rend = bcur[b];
  for (int i = rbeg + t; i < rend; i += 1024)
    atomicAdd(&hist[pairs[i] >> 17], 1);
  __syncthreads();
  int h = 0;
  if (t < 512) { h = hist[t]; sums[t] = h; }
  __syncthreads();
  for (int off = 1; off < 512; off <<= 1) {
    int u = (t < 512 && t >= off) ? sums[t - off] : 0;
    __syncthreads();
    if (t < 512) sums[t] += u;
    __syncthreads();
  }
  int base = 0; float di = 0.f;
  if (t < 512) {
    base = rbeg + sums[t] - h;          // exclusive prefix
    di = rsqrtf((float)(h + 1));
    if (t < nd) { dinv[d0 + t] = di; cur[t] = base; }
  }
  __syncthreads();

  // degree counting-sort -> sorted metadata
  if (t < 128) hist[t] = 0;
  __syncthreads();
  int c = h < 127 ? h : 127;
  if (t < nd) atomicAdd(&hist[c], 1);
  __syncthreads();
  int dv = (t < 128) ? hist[t] : 0;
  if (t < 128) sums[t] = dv;
  __syncthreads();
  for (int off = 1; off < 128; off <<= 1) {
    int u = (t < 128 && t >= off) ? sums[t - off] : 0;
    __syncthreads();
    if (t < 128) sums[t] += u;
    __syncthreads();
  }
  if (t < 128) hist[128 + t] = sums[t] - dv;
  __syncthreads();
  if (t < nd) {
    int pos = d0 + atomicAdd(&hist[128 + c], 1);
    sbeg[pos] = base; send[pos] = base + h; sdinv[pos] = di; sdn[pos] = d0 + t;
  }
  __syncthreads();

  for (int i = rbeg + t; i < rend; i += 1024) {
    unsigned pk = pairs[i];
    int q = atomicAdd(&cur[pk >> 17], 1);
    csr[q] = pk & 0x1FFFF;
  }
}

// ---------------- combined misc prep: init bcur, weight transposes ----------------
// widened: 35 blocks (bcur:1, Wt transposes: 4 mats x 8 chunks, W2t: 2 chunks)

__global__ __launch_bounds__(256) void prep_misc_kernel(
    const float* __restrict__ lin1_w, const float* __restrict__ gcn_w,
    const float* __restrict__ lin2_w, int* __restrict__ bcur,
    unsigned short* __restrict__ Wt, unsigned short* __restrict__ W2t) {
  int b = blockIdx.x;
  int t = threadIdx.x;
  if (b == 0) {
    if (t < NBUCK) bcur[t] = t * BCAP;
  } else if (b <= 32) {
    int m = (b - 1) >> 3;        // which 128x128 matrix (0..3)
    int chunk = (b - 1) & 7;     // which eighth of it
    const float* src = (m == 0) ? lin1_w : (gcn_w + (size_t)(m - 1) * 16384);
    unsigned short* dstp = Wt + (size_t)m * 16384;
    int i0 = chunk * 2048;
    for (int i = i0 + t; i < i0 + 2048; i += 256) {
      int n = i >> 7, k = i & 127;
      dstp[(size_t)n * 128 + k] = bf16r(src[(size_t)k * 128 + n]);
    }
  } else {
    int chunk = b - 33;          // 0..1
    int i0 = chunk * 3072;
    for (int i = i0 + t; i < i0 + 3072; i += 256) {
      int n = i >> 7, k = i & 127;
      W2t[i] = (n < OUTC) ? bf16r(lin2_w[(size_t)k * OUTC + n]) : (unsigned short)0;
    }
  }
}

// ---------------- MFMA GEMM (operand-swapped epilogue) ----------------
// D = mfma(a=Wt_frag, b=A_frag): lane (quad,m16) holds, per (rt,ct),
// output row = row0 + rt*16 + m16, cols = colbase + ct*16 + quad*4 + j.
// -> packed stores: fp8 = 1 uint per (rt,ct); bf16 = 1 uint2.
// MODE 0: A bf16 -> Y16 = relu(acc+bias); MODE 1: A bf16 -> Y8 = fp8(dinv*acc);
// MODE 2: A fp32 (in-flight bf16 cvt) -> Y16 = relu(acc+bias).

template <int MODE>
__global__ __launch_bounds__(256) void gemm_mfma_kernel(
    const void* __restrict__ Av, const unsigned short* __restrict__ Wt,
    const float* __restrict__ bias, const float* __restrict__ dinv,
    void* __restrict__ Y, int M) {
  int t = threadIdx.x;
  int w = t >> 6;
  int l = t & 63;
  int quad = l >> 4;
  int m16 = l & 15;
  int row0 = blockIdx.x * 64;
  int colbase = w * 32;

  floatx4 acc[4][2];
#pragma unroll
  for (int rt = 0; rt < 4; rt++)
#pragma unroll
    for (int ct = 0; ct < 2; ct++) acc[rt][ct] = (floatx4)0.f;

#pragma unroll
  for (int kc = 0; kc < 4; kc++) {
    int kof = kc * 32 + quad * 8;
    short8 a0 = *(const short8*)(Wt + (size_t)(colbase + m16) * 128 + kof);
    short8 a1 = *(const short8*)(Wt + (size_t)(colbase + 16 + m16) * 128 + kof);
#pragma unroll
    for (int rt = 0; rt < 4; rt++) {
      short8 bfr;
      if (MODE == 2) {
        const float* Af = (const float*)Av + (size_t)(row0 + rt * 16 + m16) * 128 + kof;
        float4 f0 = *(const float4*)Af;
        float4 f1 = *(const float4*)(Af + 4);
        unsigned u0 = pack_bf16x2(f0.x, f0.y);
        unsigned u1 = pack_bf16x2(f0.z, f0.w);
        unsigned u2 = pack_bf16x2(f1.x, f1.y);
        unsigned u3 = pack_bf16x2(f1.z, f1.w);
        bfr[0] = (short)(u0 & 0xFFFF); bfr[1] = (short)(u0 >> 16);
        bfr[2] = (short)(u1 & 0xFFFF); bfr[3] = (short)(u1 >> 16);
        bfr[4] = (short)(u2 & 0xFFFF); bfr[5] = (short)(u2 >> 16);
        bfr[6] = (short)(u3 & 0xFFFF); bfr[7] = (short)(u3 >> 16);
      } else {
        bfr = *(const short8*)((const unsigned short*)Av +
                               (size_t)(row0 + rt * 16 + m16) * 128 + kof);
      }
      acc[rt][0] = __builtin_amdgcn_mfma_f32_16x16x32_bf16(a0, bfr, acc[rt][0], 0, 0, 0);
      acc[rt][1] = __builtin_amdgcn_mfma_f32_16x16x32_bf16(a1, bfr, acc[rt][1], 0, 0, 0);
    }
  }

  if (MODE != 1) {
    unsigned short* Y16 = (unsigned short*)Y;
    float4 bv0 = *(const float4*)(bias + colbase + quad * 4);
    float4 bv1 = *(const float4*)(bias + colbase + 16 + quad * 4);
#pragma unroll
    for (int rt = 0; rt < 4; rt++) {
      int row = row0 + rt * 16 + m16;
      if (row < M) {
        uint2 s0, s1;
        s0.x = pack_bf16x2(fmaxf(acc[rt][0][0] + bv0.x, 0.f),
                           fmaxf(acc[rt][0][1] + bv0.y, 0.f));
        s0.y = pack_bf16x2(fmaxf(acc[rt][0][2] + bv0.z, 0.f),
                           fmaxf(acc[rt][0][3] + bv0.w, 0.f));
        s1.x = pack_bf16x2(fmaxf(acc[rt][1][0] + bv1.x, 0.f),
                           fmaxf(acc[rt][1][1] + bv1.y, 0.f));
        s1.y = pack_bf16x2(fmaxf(acc[rt][1][2] + bv1.z, 0.f),
                           fmaxf(acc[rt][1][3] + bv1.w, 0.f));
        *(uint2*)(Y16 + (size_t)row * 128 + colbase + quad * 4) = s0;
        *(uint2*)(Y16 + (size_t)row * 128 + colbase + 16 + quad * 4) = s1;
      }
    }
  } else {
    unsigned* Y8 = (unsigned*)Y;  // 32 uints per row
#pragma unroll
    for (int rt = 0; rt < 4; rt++) {
      int row = row0 + rt * 16 + m16;
      if (row < M) {
        float dd = dinv[row];
        unsigned u0 = 0, u1 = 0;
        u0 = __builtin_amdgcn_cvt_pk_fp8_f32(acc[rt][0][0] * dd, acc[rt][0][1] * dd, (int)u0, false);
        u0 = __builtin_amdgcn_cvt_pk_fp8_f32(acc[rt][0][2] * dd, acc[rt][0][3] * dd, (int)u0, true);
        u1 = __builtin_amdgcn_cvt_pk_fp8_f32(acc[rt][1][0] * dd, acc[rt][1][1] * dd, (int)u1, false);
        u1 = __builtin_amdgcn_cvt_pk_fp8_f32(acc[rt][1][2] * dd, acc[rt][1][3] * dd, (int)u1, true);
        Y8[(size_t)row * 32 + (colbase >> 2) + quad] = u0;
        Y8[(size_t)row * 32 + ((colbase + 16) >> 2) + quad] = u1;
      }
    }
  }
}

// ---------------- aggregation: 8 lanes own one node, sorted metadata ----------------
// 256-thread blocks, unroll-8 gathers with index prefetch.
// R5: output stores are NON-TEMPORAL (bypass L2). The 25.6MB output stream was
// evicting the 12.8MB gather table from the per-XCD 4MB L2s (write-allocate
// pollution) -- the gather is service-rate-bound on L2 misses, so protecting
// table residency is the lever. Stores are wave-contiguous full 64B lines, so
// nt carries no partial-line risk.

#define ACC8(u)                                                       \
  acc[0] += __builtin_amdgcn_cvt_pk_f32_fp8((int)(u).x, false);       \
  acc[1] += __builtin_amdgcn_cvt_pk_f32_fp8((int)(u).x, true);        \
  acc[2] += __builtin_amdgcn_cvt_pk_f32_fp8((int)(u).y, false);       \
  acc[3] += __builtin_amdgcn_cvt_pk_f32_fp8((int)(u).y, true);        \
  acc[4] += __builtin_amdgcn_cvt_pk_f32_fp8((int)(u).z, false);       \
  acc[5] += __builtin_amdgcn_cvt_pk_f32_fp8((int)(u).z, true);        \
  acc[6] += __builtin_amdgcn_cvt_pk_f32_fp8((int)(u).w, false);       \
  acc[7] += __builtin_amdgcn_cvt_pk_f32_fp8((int)(u).w, true);

__global__ __launch_bounds__(256) void aggregate_fp8_kernel(
    const uint4* __restrict__ Ht8, const int* __restrict__ csr,
    const int* __restrict__ sbeg, const int* __restrict__ send,
    const float* __restrict__ sdinv, const int* __restrict__ sdn,
    const float* __restrict__ bias, uint4* __restrict__ Out, int N) {
  int wid = (blockIdx.x * blockDim.x + threadIdx.x) >> 6;
  int lane = threadIdx.x & 63;
  int g = lane >> 3;
  int c8 = lane & 7;
  int idx = wid * 8 + g;
  if (idx >= N) return;
  int beg = sbeg[idx], end = send[idx];
  int d = sdn[idx];

  floatx2 acc[8];
  {
    uint4 us = Ht8[(size_t)d * 8 + c8];
    acc[0] = __builtin_amdgcn_cvt_pk_f32_fp8((int)us.x, false);
    acc[1] = __builtin_amdgcn_cvt_pk_f32_fp8((int)us.x, true);
    acc[2] = __builtin_amdgcn_cvt_pk_f32_fp8((int)us.y, false);
    acc[3] = __builtin_amdgcn_cvt_pk_f32_fp8((int)us.y, true);
    acc[4] = __builtin_amdgcn_cvt_pk_f32_fp8((int)us.z, false);
    acc[5] = __builtin_amdgcn_cvt_pk_f32_fp8((int)us.z, true);
    acc[6] = __builtin_amdgcn_cvt_pk_f32_fp8((int)us.w, false);
    acc[7] = __builtin_amdgcn_cvt_pk_f32_fp8((int)us.w, true);
  }
  int i = beg;
  int s0, s1, s2, s3, s4, s5, s6, s7;
  if (i + 7 < end) {
    s0 = csr[i];     s1 = csr[i + 1]; s2 = csr[i + 2]; s3 = csr[i + 3];
    s4 = csr[i + 4]; s5 = csr[i + 5]; s6 = csr[i + 6]; s7 = csr[i + 7];
  }
  while (i + 7 < end) {
    uint4 u0 = Ht8[(size_t)s0 * 8 + c8];
    uint4 u1 = Ht8[(size_t)s1 * 8 + c8];
    uint4 u2 = Ht8[(size_t)s2 * 8 + c8];
    uint4 u3 = Ht8[(size_t)s3 * 8 + c8];
    uint4 u4 = Ht8[(size_t)s4 * 8 + c8];
    uint4 u5 = Ht8[(size_t)s5 * 8 + c8];
    uint4 u6 = Ht8[(size_t)s6 * 8 + c8];
    uint4 u7 = Ht8[(size_t)s7 * 8 + c8];
    i += 8;
    if (i + 7 < end) {
      s0 = csr[i];     s1 = csr[i + 1]; s2 = csr[i + 2]; s3 = csr[i + 3];
      s4 = csr[i + 4]; s5 = csr[i + 5]; s6 = csr[i + 6]; s7 = csr[i + 7];
    }
    ACC8(u0) ACC8(u1) ACC8(u2) ACC8(u3) ACC8(u4) ACC8(u5) ACC8(u6) ACC8(u7)
  }
  if (i + 3 < end) {
    int t0 = csr[i], t1 = csr[i + 1], t2 = csr[i + 2], t3 = csr[i + 3];
    uint4 u0 = Ht8[(size_t)t0 * 8 + c8];
    uint4 u1 = Ht8[(size_t)t1 * 8 + c8];
    uint4 u2 = Ht8[(size_t)t2 * 8 + c8];
    uint4 u3 = Ht8[(size_t)t3 * 8 + c8];
    ACC8(u0) ACC8(u1) ACC8(u2) ACC8(u3)
    i += 4;
  }
  for (; i < end; ++i) {
    uint4 u0 = Ht8[(size_t)csr[i] * 8 + c8];
    ACC8(u0)
  }

  float dd = sdinv[idx];
  const float4* b4 = (const float4*)bias;
  float4 bv0 = b4[4 * c8 + 0];
  float4 bv1 = b4[4 * c8 + 1];
  float4 bv2 = b4[4 * c8 + 2];
  float4 bv3 = b4[4 * c8 + 3];
  uintx4 o0, o1;
  o0.x = pack_bf16x2(fmaxf(fmaf(dd, acc[0][0], bv0.x), 0.f),
                     fmaxf(fmaf(dd, acc[0][1], bv0.y), 0.f));
  o0.y = pack_bf16x2(fmaxf(fmaf(dd, acc[1][0], bv0.z), 0.f),
                     fmaxf(fmaf(dd, acc[1][1], bv0.w), 0.f));
  o0.z = pack_bf16x2(fmaxf(fmaf(dd, acc[2][0], bv1.x), 0.f),
                     fmaxf(fmaf(dd, acc[2][1], bv1.y), 0.f));
  o0.w = pack_bf16x2(fmaxf(fmaf(dd, acc[3][0], bv1.z), 0.f),
                     fmaxf(fmaf(dd, acc[3][1], bv1.w), 0.f));
  o1.x = pack_bf16x2(fmaxf(fmaf(dd, acc[4][0], bv2.x), 0.f),
                     fmaxf(fmaf(dd, acc[4][1], bv2.y), 0.f));
  o1.y = pack_bf16x2(fmaxf(fmaf(dd, acc[5][0], bv2.z), 0.f),
                     fmaxf(fmaf(dd, acc[5][1], bv2.w), 0.f));
  o1.z = pack_bf16x2(fmaxf(fmaf(dd, acc[6][0], bv3.x), 0.f),
                     fmaxf(fmaf(dd, acc[6][1], bv3.y), 0.f));
  o1.w = pack_bf16x2(fmaxf(fmaf(dd, acc[7][0], bv3.z), 0.f),
                     fmaxf(fmaf(dd, acc[7][1], bv3.w), 0.f));
  __builtin_nontemporal_store(o0, (uintx4*)(Out + (size_t)d * 16 + 2 * c8));
  __builtin_nontemporal_store(o1, (uintx4*)(Out + (size_t)d * 16 + 2 * c8 + 1));
}

// ---------------- head: MFMA logits + LDS log_softmax ----------------

__global__ __launch_bounds__(256) void head_mfma_kernel(
    const unsigned short* __restrict__ A, const unsigned short* __restrict__ W2t,
    const float* __restrict__ b2, float* __restrict__ Out, int N) {
  __shared__ float lg[64][48];
  __shared__ float bs[48];
  int t = threadIdx.x;
  int w = t >> 6, l = t & 63, quad = l >> 4, m16 = l & 15;
  if (t < 48) bs[t] = (t < OUTC) ? b2[t] : 0.f;
  int row0 = blockIdx.x * 64;

  floatx4 acc[3];
  acc[0] = (floatx4)0.f; acc[1] = (floatx4)0.f; acc[2] = (floatx4)0.f;
  const unsigned short* Aw = A + (size_t)(row0 + w * 16) * 128;
#pragma unroll
  for (int kc = 0; kc < 4; kc++) {
    int kof = kc * 32 + quad * 8;
    short8 a = *(const short8*)(Aw + (size_t)m16 * 128 + kof);
#pragma unroll
    for (int ct = 0; ct < 3; ct++) {
      short8 b = *(const short8*)(W2t + (size_t)(ct * 16 + m16) * 128 + kof);
      acc[ct] = __builtin_amdgcn_mfma_f32_16x16x32_bf16(a, b, acc[ct], 0, 0, 0);
    }
  }
#pragma unroll
  for (int ct = 0; ct < 3; ct++)
#pragma unroll
    for (int j = 0; j < 4; j++)
      lg[w * 16 + quad * 4 + j][ct * 16 + m16] = acc[ct][j];
  __syncthreads();

  int r = t >> 2, sub = t & 3;
  int row = row0 + r;
  float vals[10];
  float mx = -3.4e38f;
#pragma unroll
  for (int j = 0; j < 10; j++) {
    float v = lg[r][sub * 10 + j] + bs[sub * 10 + j];
    vals[j] = v;
    mx = fmaxf(mx, v);
  }
  mx = fmaxf(mx, __shfl_xor(mx, 1, 64));
  mx = fmaxf(mx, __shfl_xor(mx, 2, 64));
  float se = 0.f;
#pragma unroll
  for (int j = 0; j < 10; j++) se += expf(vals[j] - mx);
  se += __shfl_xor(se, 1, 64);
  se += __shfl_xor(se, 2, 64);
  if (row < N) {
    float ls = logf(se);
#pragma unroll
    for (int j = 0; j < 10; j++)
      Out[(size_t)row * OUTC + sub * 10 + j] = vals[j] - mx - ls;
  }
}

// ---------------- launch ----------------

extern "C" void kernel_launch(void* const* d_in, const int* in_sizes, int n_in,
                              void* d_out, int out_size, void* d_ws, size_t ws_size,
                              hipStream_t stream) {
  const float* x      = (const float*)d_in[0];
  const int*   edge   = (const int*)d_in[1];
  const float* lin1_w = (const float*)d_in[2];
  const float* lin1_b = (const float*)d_in[3];
  const float* gcn_w  = (const float*)d_in[4];
  const float* gcn_b  = (const float*)d_in[5];
  const float* lin2_w = (const float*)d_in[6];
  const float* lin2_b = (const float*)d_in[7];
  float* out = (float*)d_out;

  const int N = NN;
  const int E = in_sizes[1] / 2;  // 3,200,000
  const int* src = edge;
  const int* dst = edge + E;

  char* p = (char*)d_ws;
  auto alloc = [&](size_t bytes) { char* q = p; p += (bytes + 255) & ~(size_t)255; return q; };
  unsigned*       hA16    = (unsigned*)alloc((size_t)NP * 128 * 2);          // 25.6 MB
  unsigned*       hB8     = (unsigned*)alloc((size_t)NP * 32 * 4);           // 12.8 MB
  unsigned*       pairs   = (unsigned*)alloc((size_t)NBUCK * BCAP * 4);      // 14.4 MB
  int*            csr     = (int*)alloc((size_t)NBUCK * BCAP * 4);           // 14.4 MB
  float*          dinv    = (float*)alloc((size_t)NP * 4);
  int*            sbeg    = (int*)alloc((size_t)N * 4);
  int*            send    = (int*)alloc((size_t)N * 4);
  float*          sdinv   = (float*)alloc((size_t)N * 4);
  int*            sdn     = (int*)alloc((size_t)N * 4);
  unsigned short* Wt      = (unsigned short*)alloc((size_t)4 * 16384 * 2);
  unsigned short* W2t     = (unsigned short*)alloc((size_t)48 * 128 * 2);
  int*            bcur    = (int*)alloc(256 * 4);

  // prep: bcur init + weight transposes (one dispatch), then partition + fill
  prep_misc_kernel<<<35, 256, 0, stream>>>(lin1_w, gcn_w, lin2_w, bcur, Wt, W2t);
  partition_kernel<<<(E + PT_TILE - 1) / PT_TILE, 512, 0, stream>>>(src, dst, bcur, pairs, E);
  bucket_fill_kernel<<<NBUCK, 1024, 0, stream>>>(pairs, bcur, dinv, csr,
                                                 sbeg, send, sdinv, sdn, N);

  int gb = NP / 64;  // 1563
  gemm_mfma_kernel<2><<<gb, 256, 0, stream>>>((const void*)x, Wt,
                                              lin1_b, nullptr, (void*)hA16, N);
  int ablocks = (N / 8 + 3) / 4;  // 3125 blocks of 256 threads (4 waves)
  for (int k = 0; k < 3; k++) {
    gemm_mfma_kernel<1><<<gb, 256, 0, stream>>>((const void*)hA16,
                                                Wt + (size_t)(k + 1) * 16384,
                                                nullptr, dinv, (void*)hB8, N);
    aggregate_fp8_kernel<<<ablocks, 256, 0, stream>>>(
        (const uint4*)hB8, csr, sbeg, send, sdinv, sdn, gcn_b + (size_t)k * 128,
        (uint4*)hA16, N);
  }
  head_mfma_kernel<<<gb, 256, 0, stream>>>((const unsigned short*)hA16, W2t,
                                           lin2_b, out, N);
}

// Round 6
// 479.946 us; speedup vs baseline: 1.0041x; 1.0041x over previous
//
#include <hip/hip_runtime.h>
#include <math.h>

#define NN 100000
#define NP 100032              // padded to 64-row multiple (1563 * 64)
#define HIDC 128
#define OUTC 40
#define NBUCK ((NN + 511) >> 9)   // 196 buckets of 512 dst nodes
#define PT_TILE 4096
#define BCAP 18368             // fixed per-bucket pairs capacity (mean 16327, sigma~127)
#define NRG 8                  // src ranges for L2 temporal blocking
#define RGDIV 12504            // 8 * 12504 = 100032 >= NN

typedef __attribute__((ext_vector_type(2))) float floatx2;
typedef __attribute__((ext_vector_type(4))) float floatx4;
typedef __attribute__((ext_vector_type(8))) short short8;
typedef __attribute__((ext_vector_type(4))) unsigned uintx4;

// bf16 helpers (RN) -------------------------------------------------------
__device__ __forceinline__ unsigned pack_bf16x2(float a, float b) {
  unsigned ua = __float_as_uint(a), ub = __float_as_uint(b);
  ua = ua + 0x7fff + ((ua >> 16) & 1);
  ub = ub + 0x7fff + ((ub >> 16) & 1);
  return (ua >> 16) | (ub & 0xffff0000u);
}
__device__ __forceinline__ unsigned short bf16r(float x) {
  unsigned u = __float_as_uint(x);
  u = u + 0x7fff + ((u >> 16) & 1);
  return (unsigned short)(u >> 16);
}

// ---------------- graph prep (bucket-based, fixed-capacity runs) ----------------
// LDS-staged counting sort (R4): regs->LDS-sorted->LINEAR global write.

__global__ __launch_bounds__(512) void partition_kernel(
    const int* __restrict__ src, const int* __restrict__ dst,
    int* __restrict__ bcur, unsigned* __restrict__ pairs, int E) {
  __shared__ int hist[256];
  __shared__ int lcur[256];
  __shared__ int startl[256];   // local exclusive prefix (then searched)
  __shared__ int gofs[256];     // global_base[b] - startl[b]
  __shared__ unsigned lbuf[PT_TILE];  // 16 KB
  int t = threadIdx.x;
  if (t < 256) { hist[t] = 0; lcur[t] = 0; }
  __syncthreads();
  int e0 = blockIdx.x * PT_TILE;
  int ec = E - e0; if (ec > PT_TILE) ec = PT_TILE;

  // pass 1: load edges to regs + bucket histogram
  int dr[8], sr[8];
#pragma unroll
  for (int k = 0; k < 8; k++) {
    int i = t + (k << 9);
    if (i < ec) {
      int d = dst[e0 + i];
      dr[k] = d; sr[k] = src[e0 + i];
      atomicAdd(&hist[d >> 9], 1);
    }
  }
  __syncthreads();

  // inclusive scan of hist over 256 (first 256 threads), then exclusive + base
  int h = (t < 256) ? hist[t] : 0;
  if (t < 256) startl[t] = h;
  __syncthreads();
  for (int off = 1; off < 256; off <<= 1) {
    int u = (t < 256 && t >= off) ? startl[t - off] : 0;
    __syncthreads();
    if (t < 256) startl[t] += u;
    __syncthreads();
  }
  if (t < 256) {
    int st = startl[t] - h;          // exclusive start
    int gb = (h > 0) ? atomicAdd(&bcur[t], h) : 0;
    gofs[t] = gb - st;
    startl[t] = st;
  }
  __syncthreads();

  // pass 2: scatter into LDS (random LDS is cheap)
#pragma unroll
  for (int k = 0; k < 8; k++) {
    int i = t + (k << 9);
    if (i < ec) {
      int d = dr[k];
      int b = d >> 9;
      int q = atomicAdd(&lcur[b], 1);
      lbuf[startl[b] + q] = ((unsigned)(d & 511) << 17) | (unsigned)sr[k];
    }
  }
  __syncthreads();

  // pass 3: linear coalesced write-out; binary search owning bucket
  for (int pos = t; pos < ec; pos += 512) {
    int lo = 0, hi = 255;
    while (lo < hi) {
      int mid = (lo + hi + 1) >> 1;
      if (startl[mid] <= pos) lo = mid; else hi = mid - 1;
    }
    pairs[gofs[lo] + pos] = lbuf[pos];
  }
}

// per-bucket: LDS hist(512xNRG)+scan -> dinv/cur; degree counting-sort emits
// sorted metadata (sbeg/send/sdinv/sdn); then csr scatter with LDS cursors,
// ordered by SRC-RANGE within each node's run (R6): threads walk their runs
// sequentially, so range-major order makes all CUs sweep the 12.8MB gather
// table front-to-back in loose lockstep -> instantaneous per-XCD working set
// ~1.6-4MB (fits 4MB L2) instead of 12.8MB -> capacity misses become hits.
__global__ __launch_bounds__(1024) void bucket_fill_kernel(
    const unsigned* __restrict__ pairs, const int* __restrict__ bcur,
    float* __restrict__ dinv, int* __restrict__ csr,
    int* __restrict__ sbeg, int* __restrict__ send,
    float* __restrict__ sdinv, int* __restrict__ sdn, int N) {
  int b = blockIdx.x;
  int d0 = b << 9;
  int nd = N - d0; if (nd > 512) nd = 512;
  __shared__ int hist8[512 * NRG];  // 16 KB
  __shared__ int cur8[512 * NRG];   // 16 KB
  __shared__ int sums[512];
  __shared__ int dh[256];           // degree hist + cursors
  int t = threadIdx.x;
#pragma unroll
  for (int k = 0; k < NRG / 2; k++) hist8[t + k * 1024] = 0;
  __syncthreads();
  int rbeg = b * BCAP, rend = bcur[b];
  for (int i = rbeg + t; i < rend; i += 1024) {
    unsigned pk = pairs[i];
    atomicAdd(&hist8[(int)(pk >> 17) * NRG + (int)(pk & 0x1FFFF) / RGDIV], 1);
  }
  __syncthreads();
  int h = 0;
  int hr[NRG];
  if (t < 512) {
#pragma unroll
    for (int r = 0; r < NRG; r++) { hr[r] = hist8[t * NRG + r]; h += hr[r]; }
    sums[t] = h;
  }
  __syncthreads();
  for (int off = 1; off < 512; off <<= 1) {
    int u = (t < 512 && t >= off) ? sums[t - off] : 0;
    __syncthreads();
    if (t < 512) sums[t] += u;
    __syncthreads();
  }
  int base = 0; float di = 0.f;
  if (t < 512) {
    base = rbeg + sums[t] - h;          // exclusive prefix
    di = rsqrtf((float)(h + 1));
    int a = base;
#pragma unroll
    for (int r = 0; r < NRG; r++) { cur8[t * NRG + r] = a; a += hr[r]; }
    if (t < nd) dinv[d0 + t] = di;
  }
  __syncthreads();

  // degree counting-sort -> sorted metadata
  if (t < 128) dh[t] = 0;
  __syncthreads();
  int c = h < 127 ? h : 127;
  if (t < nd) atomicAdd(&dh[c], 1);
  __syncthreads();
  int dv = (t < 128) ? dh[t] : 0;
  if (t < 128) sums[t] = dv;
  __syncthreads();
  for (int off = 1; off < 128; off <<= 1) {
    int u = (t < 128 && t >= off) ? sums[t - off] : 0;
    __syncthreads();
    if (t < 128) sums[t] += u;
    __syncthreads();
  }
  if (t < 128) dh[128 + t] = sums[t] - dv;
  __syncthreads();
  if (t < nd) {
    int pos = d0 + atomicAdd(&dh[128 + c], 1);
    sbeg[pos] = base; send[pos] = base + h; sdinv[pos] = di; sdn[pos] = d0 + t;
  }
  __syncthreads();

  for (int i = rbeg + t; i < rend; i += 1024) {
    unsigned pk = pairs[i];
    int srcv = (int)(pk & 0x1FFFF);
    int q = atomicAdd(&cur8[(int)(pk >> 17) * NRG + srcv / RGDIV], 1);
    csr[q] = srcv;
  }
}

// ---------------- combined misc prep: init bcur, weight transposes ----------------
// widened: 35 blocks (bcur:1, Wt transposes: 4 mats x 8 chunks, W2t: 2 chunks)

__global__ __launch_bounds__(256) void prep_misc_kernel(
    const float* __restrict__ lin1_w, const float* __restrict__ gcn_w,
    const float* __restrict__ lin2_w, int* __restrict__ bcur,
    unsigned short* __restrict__ Wt, unsigned short* __restrict__ W2t) {
  int b = blockIdx.x;
  int t = threadIdx.x;
  if (b == 0) {
    if (t < NBUCK) bcur[t] = t * BCAP;
  } else if (b <= 32) {
    int m = (b - 1) >> 3;        // which 128x128 matrix (0..3)
    int chunk = (b - 1) & 7;     // which eighth of it
    const float* src = (m == 0) ? lin1_w : (gcn_w + (size_t)(m - 1) * 16384);
    unsigned short* dstp = Wt + (size_t)m * 16384;
    int i0 = chunk * 2048;
    for (int i = i0 + t; i < i0 + 2048; i += 256) {
      int n = i >> 7, k = i & 127;
      dstp[(size_t)n * 128 + k] = bf16r(src[(size_t)k * 128 + n]);
    }
  } else {
    int chunk = b - 33;          // 0..1
    int i0 = chunk * 3072;
    for (int i = i0 + t; i < i0 + 3072; i += 256) {
      int n = i >> 7, k = i & 127;
      W2t[i] = (n < OUTC) ? bf16r(lin2_w[(size_t)k * OUTC + n]) : (unsigned short)0;
    }
  }
}

// ---------------- MFMA GEMM (operand-swapped epilogue) ----------------
// D = mfma(a=Wt_frag, b=A_frag): lane (quad,m16) holds, per (rt,ct),
// output row = row0 + rt*16 + m16, cols = colbase + ct*16 + quad*4 + j.
// -> packed stores: fp8 = 1 uint per (rt,ct); bf16 = 1 uint2.
// MODE 0: A bf16 -> Y16 = relu(acc+bias); MODE 1: A bf16 -> Y8 = fp8(dinv*acc);
// MODE 2: A fp32 (in-flight bf16 cvt) -> Y16 = relu(acc+bias).

template <int MODE>
__global__ __launch_bounds__(256) void gemm_mfma_kernel(
    const void* __restrict__ Av, const unsigned short* __restrict__ Wt,
    const float* __restrict__ bias, const float* __restrict__ dinv,
    void* __restrict__ Y, int M) {
  int t = threadIdx.x;
  int w = t >> 6;
  int l = t & 63;
  int quad = l >> 4;
  int m16 = l & 15;
  int row0 = blockIdx.x * 64;
  int colbase = w * 32;

  floatx4 acc[4][2];
#pragma unroll
  for (int rt = 0; rt < 4; rt++)
#pragma unroll
    for (int ct = 0; ct < 2; ct++) acc[rt][ct] = (floatx4)0.f;

#pragma unroll
  for (int kc = 0; kc < 4; kc++) {
    int kof = kc * 32 + quad * 8;
    short8 a0 = *(const short8*)(Wt + (size_t)(colbase + m16) * 128 + kof);
    short8 a1 = *(const short8*)(Wt + (size_t)(colbase + 16 + m16) * 128 + kof);
#pragma unroll
    for (int rt = 0; rt < 4; rt++) {
      short8 bfr;
      if (MODE == 2) {
        const float* Af = (const float*)Av + (size_t)(row0 + rt * 16 + m16) * 128 + kof;
        float4 f0 = *(const float4*)Af;
        float4 f1 = *(const float4*)(Af + 4);
        unsigned u0 = pack_bf16x2(f0.x, f0.y);
        unsigned u1 = pack_bf16x2(f0.z, f0.w);
        unsigned u2 = pack_bf16x2(f1.x, f1.y);
        unsigned u3 = pack_bf16x2(f1.z, f1.w);
        bfr[0] = (short)(u0 & 0xFFFF); bfr[1] = (short)(u0 >> 16);
        bfr[2] = (short)(u1 & 0xFFFF); bfr[3] = (short)(u1 >> 16);
        bfr[4] = (short)(u2 & 0xFFFF); bfr[5] = (short)(u2 >> 16);
        bfr[6] = (short)(u3 & 0xFFFF); bfr[7] = (short)(u3 >> 16);
      } else {
        bfr = *(const short8*)((const unsigned short*)Av +
                               (size_t)(row0 + rt * 16 + m16) * 128 + kof);
      }
      acc[rt][0] = __builtin_amdgcn_mfma_f32_16x16x32_bf16(a0, bfr, acc[rt][0], 0, 0, 0);
      acc[rt][1] = __builtin_amdgcn_mfma_f32_16x16x32_bf16(a1, bfr, acc[rt][1], 0, 0, 0);
    }
  }

  if (MODE != 1) {
    unsigned short* Y16 = (unsigned short*)Y;
    float4 bv0 = *(const float4*)(bias + colbase + quad * 4);
    float4 bv1 = *(const float4*)(bias + colbase + 16 + quad * 4);
#pragma unroll
    for (int rt = 0; rt < 4; rt++) {
      int row = row0 + rt * 16 + m16;
      if (row < M) {
        uint2 s0, s1;
        s0.x = pack_bf16x2(fmaxf(acc[rt][0][0] + bv0.x, 0.f),
                           fmaxf(acc[rt][0][1] + bv0.y, 0.f));
        s0.y = pack_bf16x2(fmaxf(acc[rt][0][2] + bv0.z, 0.f),
                           fmaxf(acc[rt][0][3] + bv0.w, 0.f));
        s1.x = pack_bf16x2(fmaxf(acc[rt][1][0] + bv1.x, 0.f),
                           fmaxf(acc[rt][1][1] + bv1.y, 0.f));
        s1.y = pack_bf16x2(fmaxf(acc[rt][1][2] + bv1.z, 0.f),
                           fmaxf(acc[rt][1][3] + bv1.w, 0.f));
        *(uint2*)(Y16 + (size_t)row * 128 + colbase + quad * 4) = s0;
        *(uint2*)(Y16 + (size_t)row * 128 + colbase + 16 + quad * 4) = s1;
      }
    }
  } else {
    unsigned* Y8 = (unsigned*)Y;  // 32 uints per row
#pragma unroll
    for (int rt = 0; rt < 4; rt++) {
      int row = row0 + rt * 16 + m16;
      if (row < M) {
        float dd = dinv[row];
        unsigned u0 = 0, u1 = 0;
        u0 = __builtin_amdgcn_cvt_pk_fp8_f32(acc[rt][0][0] * dd, acc[rt][0][1] * dd, (int)u0, false);
        u0 = __builtin_amdgcn_cvt_pk_fp8_f32(acc[rt][0][2] * dd, acc[rt][0][3] * dd, (int)u0, true);
        u1 = __builtin_amdgcn_cvt_pk_fp8_f32(acc[rt][1][0] * dd, acc[rt][1][1] * dd, (int)u1, false);
        u1 = __builtin_amdgcn_cvt_pk_fp8_f32(acc[rt][1][2] * dd, acc[rt][1][3] * dd, (int)u1, true);
        Y8[(size_t)row * 32 + (colbase >> 2) + quad] = u0;
        Y8[(size_t)row * 32 + ((colbase + 16) >> 2) + quad] = u1;
      }
    }
  }
}

// ---------------- aggregation: 8 lanes own one node, sorted metadata ----------------
// 256-thread blocks, unroll-8 gathers with index prefetch, nt stores.
// Duration model (R0-R5): dur == FETCH_SIZE / 2.7 TB/s (random-line miss
// service rate). csr is now src-range-ordered (see bucket_fill) so the table
// sweep is temporally blocked; no code change needed here.

#define ACC8(u)                                                       \
  acc[0] += __builtin_amdgcn_cvt_pk_f32_fp8((int)(u).x, false);       \
  acc[1] += __builtin_amdgcn_cvt_pk_f32_fp8((int)(u).x, true);        \
  acc[2] += __builtin_amdgcn_cvt_pk_f32_fp8((int)(u).y, false);       \
  acc[3] += __builtin_amdgcn_cvt_pk_f32_fp8((int)(u).y, true);        \
  acc[4] += __builtin_amdgcn_cvt_pk_f32_fp8((int)(u).z, false);       \
  acc[5] += __builtin_amdgcn_cvt_pk_f32_fp8((int)(u).z, true);        \
  acc[6] += __builtin_amdgcn_cvt_pk_f32_fp8((int)(u).w, false);       \
  acc[7] += __builtin_amdgcn_cvt_pk_f32_fp8((int)(u).w, true);

__global__ __launch_bounds__(256) void aggregate_fp8_kernel(
    const uint4* __restrict__ Ht8, const int* __restrict__ csr,
    const int* __restrict__ sbeg, const int* __restrict__ send,
    const float* __restrict__ sdinv, const int* __restrict__ sdn,
    const float* __restrict__ bias, uint4* __restrict__ Out, int N) {
  int wid = (blockIdx.x * blockDim.x + threadIdx.x) >> 6;
  int lane = threadIdx.x & 63;
  int g = lane >> 3;
  int c8 = lane & 7;
  int idx = wid * 8 + g;
  if (idx >= N) return;
  int beg = sbeg[idx], end = send[idx];
  int d = sdn[idx];

  floatx2 acc[8];
  {
    uint4 us = Ht8[(size_t)d * 8 + c8];
    acc[0] = __builtin_amdgcn_cvt_pk_f32_fp8((int)us.x, false);
    acc[1] = __builtin_amdgcn_cvt_pk_f32_fp8((int)us.x, true);
    acc[2] = __builtin_amdgcn_cvt_pk_f32_fp8((int)us.y, false);
    acc[3] = __builtin_amdgcn_cvt_pk_f32_fp8((int)us.y, true);
    acc[4] = __builtin_amdgcn_cvt_pk_f32_fp8((int)us.z, false);
    acc[5] = __builtin_amdgcn_cvt_pk_f32_fp8((int)us.z, true);
    acc[6] = __builtin_amdgcn_cvt_pk_f32_fp8((int)us.w, false);
    acc[7] = __builtin_amdgcn_cvt_pk_f32_fp8((int)us.w, true);
  }
  int i = beg;
  int s0, s1, s2, s3, s4, s5, s6, s7;
  if (i + 7 < end) {
    s0 = csr[i];     s1 = csr[i + 1]; s2 = csr[i + 2]; s3 = csr[i + 3];
    s4 = csr[i + 4]; s5 = csr[i + 5]; s6 = csr[i + 6]; s7 = csr[i + 7];
  }
  while (i + 7 < end) {
    uint4 u0 = Ht8[(size_t)s0 * 8 + c8];
    uint4 u1 = Ht8[(size_t)s1 * 8 + c8];
    uint4 u2 = Ht8[(size_t)s2 * 8 + c8];
    uint4 u3 = Ht8[(size_t)s3 * 8 + c8];
    uint4 u4 = Ht8[(size_t)s4 * 8 + c8];
    uint4 u5 = Ht8[(size_t)s5 * 8 + c8];
    uint4 u6 = Ht8[(size_t)s6 * 8 + c8];
    uint4 u7 = Ht8[(size_t)s7 * 8 + c8];
    i += 8;
    if (i + 7 < end) {
      s0 = csr[i];     s1 = csr[i + 1]; s2 = csr[i + 2]; s3 = csr[i + 3];
      s4 = csr[i + 4]; s5 = csr[i + 5]; s6 = csr[i + 6]; s7 = csr[i + 7];
    }
    ACC8(u0) ACC8(u1) ACC8(u2) ACC8(u3) ACC8(u4) ACC8(u5) ACC8(u6) ACC8(u7)
  }
  if (i + 3 < end) {
    int t0 = csr[i], t1 = csr[i + 1], t2 = csr[i + 2], t3 = csr[i + 3];
    uint4 u0 = Ht8[(size_t)t0 * 8 + c8];
    uint4 u1 = Ht8[(size_t)t1 * 8 + c8];
    uint4 u2 = Ht8[(size_t)t2 * 8 + c8];
    uint4 u3 = Ht8[(size_t)t3 * 8 + c8];
    ACC8(u0) ACC8(u1) ACC8(u2) ACC8(u3)
    i += 4;
  }
  for (; i < end; ++i) {
    uint4 u0 = Ht8[(size_t)csr[i] * 8 + c8];
    ACC8(u0)
  }

  float dd = sdinv[idx];
  const float4* b4 = (const float4*)bias;
  float4 bv0 = b4[4 * c8 + 0];
  float4 bv1 = b4[4 * c8 + 1];
  float4 bv2 = b4[4 * c8 + 2];
  float4 bv3 = b4[4 * c8 + 3];
  uintx4 o0, o1;
  o0.x = pack_bf16x2(fmaxf(fmaf(dd, acc[0][0], bv0.x), 0.f),
                     fmaxf(fmaf(dd, acc[0][1], bv0.y), 0.f));
  o0.y = pack_bf16x2(fmaxf(fmaf(dd, acc[1][0], bv0.z), 0.f),
                     fmaxf(fmaf(dd, acc[1][1], bv0.w), 0.f));
  o0.z = pack_bf16x2(fmaxf(fmaf(dd, acc[2][0], bv1.x), 0.f),
                     fmaxf(fmaf(dd, acc[2][1], bv1.y), 0.f));
  o0.w = pack_bf16x2(fmaxf(fmaf(dd, acc[3][0], bv1.z), 0.f),
                     fmaxf(fmaf(dd, acc[3][1], bv1.w), 0.f));
  o1.x = pack_bf16x2(fmaxf(fmaf(dd, acc[4][0], bv2.x), 0.f),
                     fmaxf(fmaf(dd, acc[4][1], bv2.y), 0.f));
  o1.y = pack_bf16x2(fmaxf(fmaf(dd, acc[5][0], bv2.z), 0.f),
                     fmaxf(fmaf(dd, acc[5][1], bv2.w), 0.f));
  o1.z = pack_bf16x2(fmaxf(fmaf(dd, acc[6][0], bv3.x), 0.f),
                     fmaxf(fmaf(dd, acc[6][1], bv3.y), 0.f));
  o1.w = pack_bf16x2(fmaxf(fmaf(dd, acc[7][0], bv3.z), 0.f),
                     fmaxf(fmaf(dd, acc[7][1], bv3.w), 0.f));
  __builtin_nontemporal_store(o0, (uintx4*)(Out + (size_t)d * 16 + 2 * c8));
  __builtin_nontemporal_store(o1, (uintx4*)(Out + (size_t)d * 16 + 2 * c8 + 1));
}

// ---------------- head: MFMA logits + LDS log_softmax ----------------

__global__ __launch_bounds__(256) void head_mfma_kernel(
    const unsigned short* __restrict__ A, const unsigned short* __restrict__ W2t,
    const float* __restrict__ b2, float* __restrict__ Out, int N) {
  __shared__ float lg[64][48];
  __shared__ float bs[48];
  int t = threadIdx.x;
  int w = t >> 6, l = t & 63, quad = l >> 4, m16 = l & 15;
  if (t < 48) bs[t] = (t < OUTC) ? b2[t] : 0.f;
  int row0 = blockIdx.x * 64;

  floatx4 acc[3];
  acc[0] = (floatx4)0.f; acc[1] = (floatx4)0.f; acc[2] = (floatx4)0.f;
  const unsigned short* Aw = A + (size_t)(row0 + w * 16) * 128;
#pragma unroll
  for (int kc = 0; kc < 4; kc++) {
    int kof = kc * 32 + quad * 8;
    short8 a = *(const short8*)(Aw + (size_t)m16 * 128 + kof);
#pragma unroll
    for (int ct = 0; ct < 3; ct++) {
      short8 b = *(const short8*)(W2t + (size_t)(ct * 16 + m16) * 128 + kof);
      acc[ct] = __builtin_amdgcn_mfma_f32_16x16x32_bf16(a, b, acc[ct], 0, 0, 0);
    }
  }
#pragma unroll
  for (int ct = 0; ct < 3; ct++)
#pragma unroll
    for (int j = 0; j < 4; j++)
      lg[w * 16 + quad * 4 + j][ct * 16 + m16] = acc[ct][j];
  __syncthreads();

  int r = t >> 2, sub = t & 3;
  int row = row0 + r;
  float vals[10];
  float mx = -3.4e38f;
#pragma unroll
  for (int j = 0; j < 10; j++) {
    float v = lg[r][sub * 10 + j] + bs[sub * 10 + j];
    vals[j] = v;
    mx = fmaxf(mx, v);
  }
  mx = fmaxf(mx, __shfl_xor(mx, 1, 64));
  mx = fmaxf(mx, __shfl_xor(mx, 2, 64));
  float se = 0.f;
#pragma unroll
  for (int j = 0; j < 10; j++) se += expf(vals[j] - mx);
  se += __shfl_xor(se, 1, 64);
  se += __shfl_xor(se, 2, 64);
  if (row < N) {
    float ls = logf(se);
#pragma unroll
    for (int j = 0; j < 10; j++)
      Out[(size_t)row * OUTC + sub * 10 + j] = vals[j] - mx - ls;
  }
}

// ---------------- launch ----------------

extern "C" void kernel_launch(void* const* d_in, const int* in_sizes, int n_in,
                              void* d_out, int out_size, void* d_ws, size_t ws_size,
                              hipStream_t stream) {
  const float* x      = (const float*)d_in[0];
  const int*   edge   = (const int*)d_in[1];
  const float* lin1_w = (const float*)d_in[2];
  const float* lin1_b = (const float*)d_in[3];
  const float* gcn_w  = (const float*)d_in[4];
  const float* gcn_b  = (const float*)d_in[5];
  const float* lin2_w = (const float*)d_in[6];
  const float* lin2_b = (const float*)d_in[7];
  float* out = (float*)d_out;

  const int N = NN;
  const int E = in_sizes[1] / 2;  // 3,200,000
  const int* src = edge;
  const int* dst = edge + E;

  char* p = (char*)d_ws;
  auto alloc = [&](size_t bytes) { char* q = p; p += (bytes + 255) & ~(size_t)255; return q; };
  unsigned*       hA16    = (unsigned*)alloc((size_t)NP * 128 * 2);          // 25.6 MB
  unsigned*       hB8     = (unsigned*)alloc((size_t)NP * 32 * 4);           // 12.8 MB
  unsigned*       pairs   = (unsigned*)alloc((size_t)NBUCK * BCAP * 4);      // 14.4 MB
  int*            csr     = (int*)alloc((size_t)NBUCK * BCAP * 4);           // 14.4 MB
  float*          dinv    = (float*)alloc((size_t)NP * 4);
  int*            sbeg    = (int*)alloc((size_t)N * 4);
  int*            send    = (int*)alloc((size_t)N * 4);
  float*          sdinv   = (float*)alloc((size_t)N * 4);
  int*            sdn     = (int*)alloc((size_t)N * 4);
  unsigned short* Wt      = (unsigned short*)alloc((size_t)4 * 16384 * 2);
  unsigned short* W2t     = (unsigned short*)alloc((size_t)48 * 128 * 2);
  int*            bcur    = (int*)alloc(256 * 4);

  // prep: bcur init + weight transposes (one dispatch), then partition + fill
  prep_misc_kernel<<<35, 256, 0, stream>>>(lin1_w, gcn_w, lin2_w, bcur, Wt, W2t);
  partition_kernel<<<(E + PT_TILE - 1) / PT_TILE, 512, 0, stream>>>(src, dst, bcur, pairs, E);
  bucket_fill_kernel<<<NBUCK, 1024, 0, stream>>>(pairs, bcur, dinv, csr,
                                                 sbeg, send, sdinv, sdn, N);

  int gb = NP / 64;  // 1563
  gemm_mfma_kernel<2><<<gb, 256, 0, stream>>>((const void*)x, Wt,
                                              lin1_b, nullptr, (void*)hA16, N);
  int ablocks = (N / 8 + 3) / 4;  // 3125 blocks of 256 threads (4 waves)
  for (int k = 0; k < 3; k++) {
    gemm_mfma_kernel<1><<<gb, 256, 0, stream>>>((const void*)hA16,
                                                Wt + (size_t)(k + 1) * 16384,
                                                nullptr, dinv, (void*)hB8, N);
    aggregate_fp8_kernel<<<ablocks, 256, 0, stream>>>(
        (const uint4*)hB8, csr, sbeg, send, sdinv, sdn, gcn_b + (size_t)k * 128,
        (uint4*)hA16, N);
  }
  head_mfma_kernel<<<gb, 256, 0, stream>>>((const unsigned short*)hA16, W2t,
                                           lin2_b, out, N);
}

// Round 7
// 470.553 us; speedup vs baseline: 1.0242x; 1.0200x over previous
//
#include <hip/hip_runtime.h>
#include <math.h>

#define NN 100000
#define NP 100032              // padded to 64-row multiple (1563 * 64)
#define HIDC 128
#define OUTC 40
#define NBUCK ((NN + 511) >> 9)   // 196 buckets of 512 dst nodes
#define PT_TILE 4096
#define BCAP 18368             // fixed per-bucket pairs capacity (mean 16327, sigma~127)
#define NRG 8                  // src ranges for L2 temporal blocking
#define RG_SHIFT 14            // range = src >> 14 (16384-node slices, 2.1 MB fp8 each)

typedef __attribute__((ext_vector_type(2))) float floatx2;
typedef __attribute__((ext_vector_type(4))) float floatx4;
typedef __attribute__((ext_vector_type(8))) short short8;
typedef __attribute__((ext_vector_type(4))) unsigned uintx4;

// bf16 helpers (RN) -------------------------------------------------------
__device__ __forceinline__ unsigned pack_bf16x2(float a, float b) {
  unsigned ua = __float_as_uint(a), ub = __float_as_uint(b);
  ua = ua + 0x7fff + ((ua >> 16) & 1);
  ub = ub + 0x7fff + ((ub >> 16) & 1);
  return (ua >> 16) | (ub & 0xffff0000u);
}
__device__ __forceinline__ unsigned short bf16r(float x) {
  unsigned u = __float_as_uint(x);
  u = u + 0x7fff + ((u >> 16) & 1);
  return (unsigned short)(u >> 16);
}

// ---------------- graph prep (bucket-based, fixed-capacity runs) ----------------
// LDS-staged counting sort (R4): regs->LDS-sorted->LINEAR global write.

__global__ __launch_bounds__(512) void partition_kernel(
    const int* __restrict__ src, const int* __restrict__ dst,
    int* __restrict__ bcur, unsigned* __restrict__ pairs, int E) {
  __shared__ int hist[256];
  __shared__ int lcur[256];
  __shared__ int startl[256];   // local exclusive prefix (then searched)
  __shared__ int gofs[256];     // global_base[b] - startl[b]
  __shared__ unsigned lbuf[PT_TILE];  // 16 KB
  int t = threadIdx.x;
  if (t < 256) { hist[t] = 0; lcur[t] = 0; }
  __syncthreads();
  int e0 = blockIdx.x * PT_TILE;
  int ec = E - e0; if (ec > PT_TILE) ec = PT_TILE;

  // pass 1: load edges to regs + bucket histogram
  int dr[8], sr[8];
#pragma unroll
  for (int k = 0; k < 8; k++) {
    int i = t + (k << 9);
    if (i < ec) {
      int d = dst[e0 + i];
      dr[k] = d; sr[k] = src[e0 + i];
      atomicAdd(&hist[d >> 9], 1);
    }
  }
  __syncthreads();

  // inclusive scan of hist over 256 (first 256 threads), then exclusive + base
  int h = (t < 256) ? hist[t] : 0;
  if (t < 256) startl[t] = h;
  __syncthreads();
  for (int off = 1; off < 256; off <<= 1) {
    int u = (t < 256 && t >= off) ? startl[t - off] : 0;
    __syncthreads();
    if (t < 256) startl[t] += u;
    __syncthreads();
  }
  if (t < 256) {
    int st = startl[t] - h;          // exclusive start
    int gb = (h > 0) ? atomicAdd(&bcur[t], h) : 0;
    gofs[t] = gb - st;
    startl[t] = st;
  }
  __syncthreads();

  // pass 2: scatter into LDS (random LDS is cheap)
#pragma unroll
  for (int k = 0; k < 8; k++) {
    int i = t + (k << 9);
    if (i < ec) {
      int d = dr[k];
      int b = d >> 9;
      int q = atomicAdd(&lcur[b], 1);
      lbuf[startl[b] + q] = ((unsigned)(d & 511) << 17) | (unsigned)sr[k];
    }
  }
  __syncthreads();

  // pass 3: linear coalesced write-out; binary search owning bucket
  for (int pos = t; pos < ec; pos += 512) {
    int lo = 0, hi = 255;
    while (lo < hi) {
      int mid = (lo + hi + 1) >> 1;
      if (startl[mid] <= pos) lo = mid; else hi = mid - 1;
    }
    pairs[gofs[lo] + pos] = lbuf[pos];
  }
}

// per-bucket: LDS hist(512xNRG)+scan -> dinv/cur; degree counting-sort emits
// sorted metadata (sbeg/send/sdinv/sdn); then csr scatter with LDS cursors,
// src-range-major within each node's run (R6) -> combined with the aggregate's
// band-major schedule (R7), all CUs sweep the gather table slice-by-slice.
// RG via shift (R7): range = src >> 14, no integer divides in hot loops.
__global__ __launch_bounds__(1024) void bucket_fill_kernel(
    const unsigned* __restrict__ pairs, const int* __restrict__ bcur,
    float* __restrict__ dinv, int* __restrict__ csr,
    int* __restrict__ sbeg, int* __restrict__ send,
    float* __restrict__ sdinv, int* __restrict__ sdn, int N) {
  int b = blockIdx.x;
  int d0 = b << 9;
  int nd = N - d0; if (nd > 512) nd = 512;
  __shared__ int hist8[512 * NRG];  // 16 KB
  __shared__ int cur8[512 * NRG];   // 16 KB
  __shared__ int sums[512];
  __shared__ int dh[256];           // degree hist + cursors
  int t = threadIdx.x;
#pragma unroll
  for (int k = 0; k < NRG / 2; k++) hist8[t + k * 1024] = 0;
  __syncthreads();
  int rbeg = b * BCAP, rend = bcur[b];
  for (int i = rbeg + t; i < rend; i += 1024) {
    unsigned pk = pairs[i];
    atomicAdd(&hist8[(int)(pk >> 17) * NRG + (int)((pk & 0x1FFFF) >> RG_SHIFT)], 1);
  }
  __syncthreads();
  int h = 0;
  int hr[NRG];
  if (t < 512) {
#pragma unroll
    for (int r = 0; r < NRG; r++) { hr[r] = hist8[t * NRG + r]; h += hr[r]; }
    sums[t] = h;
  }
  __syncthreads();
  for (int off = 1; off < 512; off <<= 1) {
    int u = (t < 512 && t >= off) ? sums[t - off] : 0;
    __syncthreads();
    if (t < 512) sums[t] += u;
    __syncthreads();
  }
  int base = 0; float di = 0.f;
  if (t < 512) {
    base = rbeg + sums[t] - h;          // exclusive prefix
    di = rsqrtf((float)(h + 1));
    int a = base;
#pragma unroll
    for (int r = 0; r < NRG; r++) { cur8[t * NRG + r] = a; a += hr[r]; }
    if (t < nd) dinv[d0 + t] = di;
  }
  __syncthreads();

  // degree counting-sort -> sorted metadata
  if (t < 128) dh[t] = 0;
  __syncthreads();
  int c = h < 127 ? h : 127;
  if (t < nd) atomicAdd(&dh[c], 1);
  __syncthreads();
  int dv = (t < 128) ? dh[t] : 0;
  if (t < 128) sums[t] = dv;
  __syncthreads();
  for (int off = 1; off < 128; off <<= 1) {
    int u = (t < 128 && t >= off) ? sums[t - off] : 0;
    __syncthreads();
    if (t < 128) sums[t] += u;
    __syncthreads();
  }
  if (t < 128) dh[128 + t] = sums[t] - dv;
  __syncthreads();
  if (t < nd) {
    int pos = d0 + atomicAdd(&dh[128 + c], 1);
    sbeg[pos] = base; send[pos] = base + h; sdinv[pos] = di; sdn[pos] = d0 + t;
  }
  __syncthreads();

  for (int i = rbeg + t; i < rend; i += 1024) {
    unsigned pk = pairs[i];
    int srcv = (int)(pk & 0x1FFFF);
    int q = atomicAdd(&cur8[(int)(pk >> 17) * NRG + (srcv >> RG_SHIFT)], 1);
    csr[q] = srcv;
  }
}

// ---------------- combined misc prep: init bcur, weight transposes ----------------
// widened: 35 blocks (bcur:1, Wt transposes: 4 mats x 8 chunks, W2t: 2 chunks)

__global__ __launch_bounds__(256) void prep_misc_kernel(
    const float* __restrict__ lin1_w, const float* __restrict__ gcn_w,
    const float* __restrict__ lin2_w, int* __restrict__ bcur,
    unsigned short* __restrict__ Wt, unsigned short* __restrict__ W2t) {
  int b = blockIdx.x;
  int t = threadIdx.x;
  if (b == 0) {
    if (t < NBUCK) bcur[t] = t * BCAP;
  } else if (b <= 32) {
    int m = (b - 1) >> 3;        // which 128x128 matrix (0..3)
    int chunk = (b - 1) & 7;     // which eighth of it
    const float* src = (m == 0) ? lin1_w : (gcn_w + (size_t)(m - 1) * 16384);
    unsigned short* dstp = Wt + (size_t)m * 16384;
    int i0 = chunk * 2048;
    for (int i = i0 + t; i < i0 + 2048; i += 256) {
      int n = i >> 7, k = i & 127;
      dstp[(size_t)n * 128 + k] = bf16r(src[(size_t)k * 128 + n]);
    }
  } else {
    int chunk = b - 33;          // 0..1
    int i0 = chunk * 3072;
    for (int i = i0 + t; i < i0 + 3072; i += 256) {
      int n = i >> 7, k = i & 127;
      W2t[i] = (n < OUTC) ? bf16r(lin2_w[(size_t)k * OUTC + n]) : (unsigned short)0;
    }
  }
}

// ---------------- MFMA GEMM (operand-swapped epilogue) ----------------
// D = mfma(a=Wt_frag, b=A_frag): lane (quad,m16) holds, per (rt,ct),
// output row = row0 + rt*16 + m16, cols = colbase + ct*16 + quad*4 + j.
// -> packed stores: fp8 = 1 uint per (rt,ct); bf16 = 1 uint2.
// MODE 0: A bf16 -> Y16 = relu(acc+bias); MODE 1: A bf16 -> Y8 = fp8(dinv*acc);
// MODE 2: A fp32 (in-flight bf16 cvt) -> Y16 = relu(acc+bias).

template <int MODE>
__global__ __launch_bounds__(256) void gemm_mfma_kernel(
    const void* __restrict__ Av, const unsigned short* __restrict__ Wt,
    const float* __restrict__ bias, const float* __restrict__ dinv,
    void* __restrict__ Y, int M) {
  int t = threadIdx.x;
  int w = t >> 6;
  int l = t & 63;
  int quad = l >> 4;
  int m16 = l & 15;
  int row0 = blockIdx.x * 64;
  int colbase = w * 32;

  floatx4 acc[4][2];
#pragma unroll
  for (int rt = 0; rt < 4; rt++)
#pragma unroll
    for (int ct = 0; ct < 2; ct++) acc[rt][ct] = (floatx4)0.f;

#pragma unroll
  for (int kc = 0; kc < 4; kc++) {
    int kof = kc * 32 + quad * 8;
    short8 a0 = *(const short8*)(Wt + (size_t)(colbase + m16) * 128 + kof);
    short8 a1 = *(const short8*)(Wt + (size_t)(colbase + 16 + m16) * 128 + kof);
#pragma unroll
    for (int rt = 0; rt < 4; rt++) {
      short8 bfr;
      if (MODE == 2) {
        const float* Af = (const float*)Av + (size_t)(row0 + rt * 16 + m16) * 128 + kof;
        float4 f0 = *(const float4*)Af;
        float4 f1 = *(const float4*)(Af + 4);
        unsigned u0 = pack_bf16x2(f0.x, f0.y);
        unsigned u1 = pack_bf16x2(f0.z, f0.w);
        unsigned u2 = pack_bf16x2(f1.x, f1.y);
        unsigned u3 = pack_bf16x2(f1.z, f1.w);
        bfr[0] = (short)(u0 & 0xFFFF); bfr[1] = (short)(u0 >> 16);
        bfr[2] = (short)(u1 & 0xFFFF); bfr[3] = (short)(u1 >> 16);
        bfr[4] = (short)(u2 & 0xFFFF); bfr[5] = (short)(u2 >> 16);
        bfr[6] = (short)(u3 & 0xFFFF); bfr[7] = (short)(u3 >> 16);
      } else {
        bfr = *(const short8*)((const unsigned short*)Av +
                               (size_t)(row0 + rt * 16 + m16) * 128 + kof);
      }
      acc[rt][0] = __builtin_amdgcn_mfma_f32_16x16x32_bf16(a0, bfr, acc[rt][0], 0, 0, 0);
      acc[rt][1] = __builtin_amdgcn_mfma_f32_16x16x32_bf16(a1, bfr, acc[rt][1], 0, 0, 0);
    }
  }

  if (MODE != 1) {
    unsigned short* Y16 = (unsigned short*)Y;
    float4 bv0 = *(const float4*)(bias + colbase + quad * 4);
    float4 bv1 = *(const float4*)(bias + colbase + 16 + quad * 4);
#pragma unroll
    for (int rt = 0; rt < 4; rt++) {
      int row = row0 + rt * 16 + m16;
      if (row < M) {
        uint2 s0, s1;
        s0.x = pack_bf16x2(fmaxf(acc[rt][0][0] + bv0.x, 0.f),
                           fmaxf(acc[rt][0][1] + bv0.y, 0.f));
        s0.y = pack_bf16x2(fmaxf(acc[rt][0][2] + bv0.z, 0.f),
                           fmaxf(acc[rt][0][3] + bv0.w, 0.f));
        s1.x = pack_bf16x2(fmaxf(acc[rt][1][0] + bv1.x, 0.f),
                           fmaxf(acc[rt][1][1] + bv1.y, 0.f));
        s1.y = pack_bf16x2(fmaxf(acc[rt][1][2] + bv1.z, 0.f),
                           fmaxf(acc[rt][1][3] + bv1.w, 0.f));
        *(uint2*)(Y16 + (size_t)row * 128 + colbase + quad * 4) = s0;
        *(uint2*)(Y16 + (size_t)row * 128 + colbase + 16 + quad * 4) = s1;
      }
    }
  } else {
    unsigned* Y8 = (unsigned*)Y;  // 32 uints per row
#pragma unroll
    for (int rt = 0; rt < 4; rt++) {
      int row = row0 + rt * 16 + m16;
      if (row < M) {
        float dd = dinv[row];
        unsigned u0 = 0, u1 = 0;
        u0 = __builtin_amdgcn_cvt_pk_fp8_f32(acc[rt][0][0] * dd, acc[rt][0][1] * dd, (int)u0, false);
        u0 = __builtin_amdgcn_cvt_pk_fp8_f32(acc[rt][0][2] * dd, acc[rt][0][3] * dd, (int)u0, true);
        u1 = __builtin_amdgcn_cvt_pk_fp8_f32(acc[rt][1][0] * dd, acc[rt][1][1] * dd, (int)u1, false);
        u1 = __builtin_amdgcn_cvt_pk_fp8_f32(acc[rt][1][2] * dd, acc[rt][1][3] * dd, (int)u1, true);
        Y8[(size_t)row * 32 + (colbase >> 2) + quad] = u0;
        Y8[(size_t)row * 32 + ((colbase + 16) >> 2) + quad] = u1;
      }
    }
  }
}

// ---------------- aggregation: 8 lanes own one node, sorted metadata ----------------
// R7: BAND-MAJOR wave remap (bucket = wid % NBUCK, band = wid / NBUCK).
// Co-resident waves then sit at the same degree-sorted band across all
// buckets -> equal trip counts -> equal src-range phase at every iteration.
// With range-ordered csr this makes all CUs sweep the 12.8MB table
// slice-by-slice (2.1MB per slice, fits per-XCD L2).

#define ACC8(u)                                                       \
  acc[0] += __builtin_amdgcn_cvt_pk_f32_fp8((int)(u).x, false);       \
  acc[1] += __builtin_amdgcn_cvt_pk_f32_fp8((int)(u).x, true);        \
  acc[2] += __builtin_amdgcn_cvt_pk_f32_fp8((int)(u).y, false);       \
  acc[3] += __builtin_amdgcn_cvt_pk_f32_fp8((int)(u).y, true);        \
  acc[4] += __builtin_amdgcn_cvt_pk_f32_fp8((int)(u).z, false);       \
  acc[5] += __builtin_amdgcn_cvt_pk_f32_fp8((int)(u).z, true);        \
  acc[6] += __builtin_amdgcn_cvt_pk_f32_fp8((int)(u).w, false);       \
  acc[7] += __builtin_amdgcn_cvt_pk_f32_fp8((int)(u).w, true);

__global__ __launch_bounds__(256) void aggregate_fp8_kernel(
    const uint4* __restrict__ Ht8, const int* __restrict__ csr,
    const int* __restrict__ sbeg, const int* __restrict__ send,
    const float* __restrict__ sdinv, const int* __restrict__ sdn,
    const float* __restrict__ bias, uint4* __restrict__ Out, int N) {
  int wid = (blockIdx.x * blockDim.x + threadIdx.x) >> 6;
  int lane = threadIdx.x & 63;
  int g = lane >> 3;
  int c8 = lane & 7;
  int bucket = wid % NBUCK;
  int band = wid / NBUCK;          // 0..63
  int idx = (bucket << 9) + (band << 3) + g;
  if (idx >= N) return;
  int beg = sbeg[idx], end = send[idx];
  int d = sdn[idx];

  floatx2 acc[8];
  {
    uint4 us = Ht8[(size_t)d * 8 + c8];
    acc[0] = __builtin_amdgcn_cvt_pk_f32_fp8((int)us.x, false);
    acc[1] = __builtin_amdgcn_cvt_pk_f32_fp8((int)us.x, true);
    acc[2] = __builtin_amdgcn_cvt_pk_f32_fp8((int)us.y, false);
    acc[3] = __builtin_amdgcn_cvt_pk_f32_fp8((int)us.y, true);
    acc[4] = __builtin_amdgcn_cvt_pk_f32_fp8((int)us.z, false);
    acc[5] = __builtin_amdgcn_cvt_pk_f32_fp8((int)us.z, true);
    acc[6] = __builtin_amdgcn_cvt_pk_f32_fp8((int)us.w, false);
    acc[7] = __builtin_amdgcn_cvt_pk_f32_fp8((int)us.w, true);
  }
  int i = beg;
  int s0, s1, s2, s3, s4, s5, s6, s7;
  if (i + 7 < end) {
    s0 = csr[i];     s1 = csr[i + 1]; s2 = csr[i + 2]; s3 = csr[i + 3];
    s4 = csr[i + 4]; s5 = csr[i + 5]; s6 = csr[i + 6]; s7 = csr[i + 7];
  }
  while (i + 7 < end) {
    uint4 u0 = Ht8[(size_t)s0 * 8 + c8];
    uint4 u1 = Ht8[(size_t)s1 * 8 + c8];
    uint4 u2 = Ht8[(size_t)s2 * 8 + c8];
    uint4 u3 = Ht8[(size_t)s3 * 8 + c8];
    uint4 u4 = Ht8[(size_t)s4 * 8 + c8];
    uint4 u5 = Ht8[(size_t)s5 * 8 + c8];
    uint4 u6 = Ht8[(size_t)s6 * 8 + c8];
    uint4 u7 = Ht8[(size_t)s7 * 8 + c8];
    i += 8;
    if (i + 7 < end) {
      s0 = csr[i];     s1 = csr[i + 1]; s2 = csr[i + 2]; s3 = csr[i + 3];
      s4 = csr[i + 4]; s5 = csr[i + 5]; s6 = csr[i + 6]; s7 = csr[i + 7];
    }
    ACC8(u0) ACC8(u1) ACC8(u2) ACC8(u3) ACC8(u4) ACC8(u5) ACC8(u6) ACC8(u7)
  }
  if (i + 3 < end) {
    int t0 = csr[i], t1 = csr[i + 1], t2 = csr[i + 2], t3 = csr[i + 3];
    uint4 u0 = Ht8[(size_t)t0 * 8 + c8];
    uint4 u1 = Ht8[(size_t)t1 * 8 + c8];
    uint4 u2 = Ht8[(size_t)t2 * 8 + c8];
    uint4 u3 = Ht8[(size_t)t3 * 8 + c8];
    ACC8(u0) ACC8(u1) ACC8(u2) ACC8(u3)
    i += 4;
  }
  for (; i < end; ++i) {
    uint4 u0 = Ht8[(size_t)csr[i] * 8 + c8];
    ACC8(u0)
  }

  float dd = sdinv[idx];
  const float4* b4 = (const float4*)bias;
  float4 bv0 = b4[4 * c8 + 0];
  float4 bv1 = b4[4 * c8 + 1];
  float4 bv2 = b4[4 * c8 + 2];
  float4 bv3 = b4[4 * c8 + 3];
  uintx4 o0, o1;
  o0.x = pack_bf16x2(fmaxf(fmaf(dd, acc[0][0], bv0.x), 0.f),
                     fmaxf(fmaf(dd, acc[0][1], bv0.y), 0.f));
  o0.y = pack_bf16x2(fmaxf(fmaf(dd, acc[1][0], bv0.z), 0.f),
                     fmaxf(fmaf(dd, acc[1][1], bv0.w), 0.f));
  o0.z = pack_bf16x2(fmaxf(fmaf(dd, acc[2][0], bv1.x), 0.f),
                     fmaxf(fmaf(dd, acc[2][1], bv1.y), 0.f));
  o0.w = pack_bf16x2(fmaxf(fmaf(dd, acc[3][0], bv1.z), 0.f),
                     fmaxf(fmaf(dd, acc[3][1], bv1.w), 0.f));
  o1.x = pack_bf16x2(fmaxf(fmaf(dd, acc[4][0], bv2.x), 0.f),
                     fmaxf(fmaf(dd, acc[4][1], bv2.y), 0.f));
  o1.y = pack_bf16x2(fmaxf(fmaf(dd, acc[5][0], bv2.z), 0.f),
                     fmaxf(fmaf(dd, acc[5][1], bv2.w), 0.f));
  o1.z = pack_bf16x2(fmaxf(fmaf(dd, acc[6][0], bv3.x), 0.f),
                     fmaxf(fmaf(dd, acc[6][1], bv3.y), 0.f));
  o1.w = pack_bf16x2(fmaxf(fmaf(dd, acc[7][0], bv3.z), 0.f),
                     fmaxf(fmaf(dd, acc[7][1], bv3.w), 0.f));
  __builtin_nontemporal_store(o0, (uintx4*)(Out + (size_t)d * 16 + 2 * c8));
  __builtin_nontemporal_store(o1, (uintx4*)(Out + (size_t)d * 16 + 2 * c8 + 1));
}

// ---------------- head: MFMA logits + LDS log_softmax ----------------

__global__ __launch_bounds__(256) void head_mfma_kernel(
    const unsigned short* __restrict__ A, const unsigned short* __restrict__ W2t,
    const float* __restrict__ b2, float* __restrict__ Out, int N) {
  __shared__ float lg[64][48];
  __shared__ float bs[48];
  int t = threadIdx.x;
  int w = t >> 6, l = t & 63, quad = l >> 4, m16 = l & 15;
  if (t < 48) bs[t] = (t < OUTC) ? b2[t] : 0.f;
  int row0 = blockIdx.x * 64;

  floatx4 acc[3];
  acc[0] = (floatx4)0.f; acc[1] = (floatx4)0.f; acc[2] = (floatx4)0.f;
  const unsigned short* Aw = A + (size_t)(row0 + w * 16) * 128;
#pragma unroll
  for (int kc = 0; kc < 4; kc++) {
    int kof = kc * 32 + quad * 8;
    short8 a = *(const short8*)(Aw + (size_t)m16 * 128 + kof);
#pragma unroll
    for (int ct = 0; ct < 3; ct++) {
      short8 b = *(const short8*)(W2t + (size_t)(ct * 16 + m16) * 128 + kof);
      acc[ct] = __builtin_amdgcn_mfma_f32_16x16x32_bf16(a, b, acc[ct], 0, 0, 0);
    }
  }
#pragma unroll
  for (int ct = 0; ct < 3; ct++)
#pragma unroll
    for (int j = 0; j < 4; j++)
      lg[w * 16 + quad * 4 + j][ct * 16 + m16] = acc[ct][j];
  __syncthreads();

  int r = t >> 2, sub = t & 3;
  int row = row0 + r;
  float vals[10];
  float mx = -3.4e38f;
#pragma unroll
  for (int j = 0; j < 10; j++) {
    float v = lg[r][sub * 10 + j] + bs[sub * 10 + j];
    vals[j] = v;
    mx = fmaxf(mx, v);
  }
  mx = fmaxf(mx, __shfl_xor(mx, 1, 64));
  mx = fmaxf(mx, __shfl_xor(mx, 2, 64));
  float se = 0.f;
#pragma unroll
  for (int j = 0; j < 10; j++) se += expf(vals[j] - mx);
  se += __shfl_xor(se, 1, 64);
  se += __shfl_xor(se, 2, 64);
  if (row < N) {
    float ls = logf(se);
#pragma unroll
    for (int j = 0; j < 10; j++)
      Out[(size_t)row * OUTC + sub * 10 + j] = vals[j] - mx - ls;
  }
}

// ---------------- launch ----------------

extern "C" void kernel_launch(void* const* d_in, const int* in_sizes, int n_in,
                              void* d_out, int out_size, void* d_ws, size_t ws_size,
                              hipStream_t stream) {
  const float* x      = (const float*)d_in[0];
  const int*   edge   = (const int*)d_in[1];
  const float* lin1_w = (const float*)d_in[2];
  const float* lin1_b = (const float*)d_in[3];
  const float* gcn_w  = (const float*)d_in[4];
  const float* gcn_b  = (const float*)d_in[5];
  const float* lin2_w = (const float*)d_in[6];
  const float* lin2_b = (const float*)d_in[7];
  float* out = (float*)d_out;

  const int N = NN;
  const int E = in_sizes[1] / 2;  // 3,200,000
  const int* src = edge;
  const int* dst = edge + E;

  char* p = (char*)d_ws;
  auto alloc = [&](size_t bytes) { char* q = p; p += (bytes + 255) & ~(size_t)255; return q; };
  unsigned*       hA16    = (unsigned*)alloc((size_t)NP * 128 * 2);          // 25.6 MB
  unsigned*       hB8     = (unsigned*)alloc((size_t)NP * 32 * 4);           // 12.8 MB
  unsigned*       pairs   = (unsigned*)alloc((size_t)NBUCK * BCAP * 4);      // 14.4 MB
  int*            csr     = (int*)alloc((size_t)NBUCK * BCAP * 4);           // 14.4 MB
  float*          dinv    = (float*)alloc((size_t)NP * 4);
  int*            sbeg    = (int*)alloc((size_t)N * 4);
  int*            send    = (int*)alloc((size_t)N * 4);
  float*          sdinv   = (float*)alloc((size_t)N * 4);
  int*            sdn     = (int*)alloc((size_t)N * 4);
  unsigned short* Wt      = (unsigned short*)alloc((size_t)4 * 16384 * 2);
  unsigned short* W2t     = (unsigned short*)alloc((size_t)48 * 128 * 2);
  int*            bcur    = (int*)alloc(256 * 4);

  // prep: bcur init + weight transposes (one dispatch), then partition + fill
  prep_misc_kernel<<<35, 256, 0, stream>>>(lin1_w, gcn_w, lin2_w, bcur, Wt, W2t);
  partition_kernel<<<(E + PT_TILE - 1) / PT_TILE, 512, 0, stream>>>(src, dst, bcur, pairs, E);
  bucket_fill_kernel<<<NBUCK, 1024, 0, stream>>>(pairs, bcur, dinv, csr,
                                                 sbeg, send, sdinv, sdn, N);

  int gb = NP / 64;  // 1563
  gemm_mfma_kernel<2><<<gb, 256, 0, stream>>>((const void*)x, Wt,
                                              lin1_b, nullptr, (void*)hA16, N);
  int ablocks = (NBUCK * 64) / 4;  // 3136 blocks: band-major wave space (196x64)
  for (int k = 0; k < 3; k++) {
    gemm_mfma_kernel<1><<<gb, 256, 0, stream>>>((const void*)hA16,
                                                Wt + (size_t)(k + 1) * 16384,
                                                nullptr, dinv, (void*)hB8, N);
    aggregate_fp8_kernel<<<ablocks, 256, 0, stream>>>(
        (const uint4*)hB8, csr, sbeg, send, sdinv, sdn, gcn_b + (size_t)k * 128,
        (uint4*)hA16, N);
  }
  head_mfma_kernel<<<gb, 256, 0, stream>>>((const unsigned short*)hA16, W2t,
                                           lin2_b, out, N);
}

// Round 8
// 454.843 us; speedup vs baseline: 1.0595x; 1.0345x over previous
//
#include <hip/hip_runtime.h>
#include <math.h>

#define NN 100000
#define NP 100032              // padded to 64-row multiple (1563 * 64)
#define HIDC 128
#define OUTC 40
#define NBUCK ((NN + 511) >> 9)   // 196 buckets of 512 dst nodes
#define PT_TILE 8192
#define BCAP 18368             // fixed per-bucket pairs capacity (mean 16327, sigma~127)
#define NRG 8                  // src ranges for L2 temporal blocking
#define RG_SHIFT 14            // range = src >> 14 (16384-node slices, 2.1 MB fp8 each)

typedef __attribute__((ext_vector_type(2))) float floatx2;
typedef __attribute__((ext_vector_type(4))) float floatx4;
typedef __attribute__((ext_vector_type(8))) short short8;
typedef __attribute__((ext_vector_type(4))) unsigned uintx4;

// bf16 helpers (RN) -------------------------------------------------------
__device__ __forceinline__ unsigned pack_bf16x2(float a, float b) {
  unsigned ua = __float_as_uint(a), ub = __float_as_uint(b);
  ua = ua + 0x7fff + ((ua >> 16) & 1);
  ub = ub + 0x7fff + ((ub >> 16) & 1);
  return (ua >> 16) | (ub & 0xffff0000u);
}
__device__ __forceinline__ unsigned short bf16r(float x) {
  unsigned u = __float_as_uint(x);
  u = u + 0x7fff + ((u >> 16) & 1);
  return (unsigned short)(u >> 16);
}

// ---------------- graph prep (bucket-based, fixed-capacity runs) ----------------
// LDS-staged counting sort (R4): regs->LDS-sorted->LINEAR global write.
// R8: PT_TILE 8192 (halves per-block scan fixed costs).

__global__ __launch_bounds__(512) void partition_kernel(
    const int* __restrict__ src, const int* __restrict__ dst,
    int* __restrict__ bcur, unsigned* __restrict__ pairs, int E) {
  __shared__ int hist[256];
  __shared__ int lcur[256];
  __shared__ int startl[256];   // local exclusive prefix (then searched)
  __shared__ int gofs[256];     // global_base[b] - startl[b]
  __shared__ unsigned lbuf[PT_TILE];  // 32 KB
  int t = threadIdx.x;
  if (t < 256) { hist[t] = 0; lcur[t] = 0; }
  __syncthreads();
  int e0 = blockIdx.x * PT_TILE;
  int ec = E - e0; if (ec > PT_TILE) ec = PT_TILE;

  // pass 1: load edges to regs + bucket histogram
  int dr[16], sr[16];
#pragma unroll
  for (int k = 0; k < 16; k++) {
    int i = t + (k << 9);
    if (i < ec) {
      int d = dst[e0 + i];
      dr[k] = d; sr[k] = src[e0 + i];
      atomicAdd(&hist[d >> 9], 1);
    }
  }
  __syncthreads();

  // inclusive scan of hist over 256 (first 256 threads), then exclusive + base
  int h = (t < 256) ? hist[t] : 0;
  if (t < 256) startl[t] = h;
  __syncthreads();
  for (int off = 1; off < 256; off <<= 1) {
    int u = (t < 256 && t >= off) ? startl[t - off] : 0;
    __syncthreads();
    if (t < 256) startl[t] += u;
    __syncthreads();
  }
  if (t < 256) {
    int st = startl[t] - h;          // exclusive start
    int gb = (h > 0) ? atomicAdd(&bcur[t], h) : 0;
    gofs[t] = gb - st;
    startl[t] = st;
  }
  __syncthreads();

  // pass 2: scatter into LDS (random LDS is cheap)
#pragma unroll
  for (int k = 0; k < 16; k++) {
    int i = t + (k << 9);
    if (i < ec) {
      int d = dr[k];
      int b = d >> 9;
      int q = atomicAdd(&lcur[b], 1);
      lbuf[startl[b] + q] = ((unsigned)(d & 511) << 17) | (unsigned)sr[k];
    }
  }
  __syncthreads();

  // pass 3: linear coalesced write-out; binary search owning bucket
  for (int pos = t; pos < ec; pos += 512) {
    int lo = 0, hi = 255;
    while (lo < hi) {
      int mid = (lo + hi + 1) >> 1;
      if (startl[mid] <= pos) lo = mid; else hi = mid - 1;
    }
    pairs[gofs[lo] + pos] = lbuf[pos];
  }
}

// per-bucket (R8 v3): pairs loaded into LDS ONCE (coalesced); histogram,
// scans, metadata, and a ushort permutation all built in LDS; csr written out
// LINEARLY coalesced via lbuf[perm[pos]]. Global traffic halves vs v2
// (28.8MB read + random write -> 14.4MB read + streaming write).
// csr stays src-range-major per node (R6) for the aggregate's L2 blocking.
// LDS: 73.5 + 36.7 + 16 + 16 + 2 + 1 = ~146 KB (1 block/CU; grid=196 anyway).
__global__ __launch_bounds__(1024) void bucket_fill_kernel(
    const unsigned* __restrict__ pairs, const int* __restrict__ bcur,
    float* __restrict__ dinv, int* __restrict__ csr,
    int* __restrict__ sbeg, int* __restrict__ send,
    float* __restrict__ sdinv, int* __restrict__ sdn, int N) {
  int b = blockIdx.x;
  int d0 = b << 9;
  int nd = N - d0; if (nd > 512) nd = 512;
  __shared__ unsigned lbuf[BCAP];        // 73.5 KB
  __shared__ unsigned short perm[BCAP];  // 36.7 KB
  __shared__ int hist8[512 * NRG];       // 16 KB
  __shared__ int cur8[512 * NRG];        // 16 KB
  __shared__ int sums[512];
  __shared__ int dh[256];                // degree hist + cursors
  int t = threadIdx.x;
#pragma unroll
  for (int k = 0; k < NRG / 2; k++) hist8[t + k * 1024] = 0;
  int rbeg = b * BCAP;
  int cnt = bcur[b] - rbeg;
  // load pairs into LDS (coalesced, once)
  for (int i = t; i < cnt; i += 1024) lbuf[i] = pairs[rbeg + i];
  __syncthreads();
  // histogram from LDS
  for (int i = t; i < cnt; i += 1024) {
    unsigned pk = lbuf[i];
    atomicAdd(&hist8[(int)(pk >> 17) * NRG + (int)((pk & 0x1FFFF) >> RG_SHIFT)], 1);
  }
  __syncthreads();
  int h = 0;
  int hr[NRG];
  if (t < 512) {
#pragma unroll
    for (int r = 0; r < NRG; r++) { hr[r] = hist8[t * NRG + r]; h += hr[r]; }
    sums[t] = h;
  }
  __syncthreads();
  for (int off = 1; off < 512; off <<= 1) {
    int u = (t < 512 && t >= off) ? sums[t - off] : 0;
    __syncthreads();
    if (t < 512) sums[t] += u;
    __syncthreads();
  }
  int lbase = 0; float di = 0.f;
  if (t < 512) {
    lbase = sums[t] - h;                // local exclusive prefix (0-based)
    di = rsqrtf((float)(h + 1));
    int a = lbase;
#pragma unroll
    for (int r = 0; r < NRG; r++) { cur8[t * NRG + r] = a; a += hr[r]; }
    if (t < nd) dinv[d0 + t] = di;
  }
  __syncthreads();

  // degree counting-sort -> sorted metadata
  if (t < 128) dh[t] = 0;
  __syncthreads();
  int c = h < 127 ? h : 127;
  if (t < nd) atomicAdd(&dh[c], 1);
  __syncthreads();
  int dv = (t < 128) ? dh[t] : 0;
  if (t < 128) sums[t] = dv;
  __syncthreads();
  for (int off = 1; off < 128; off <<= 1) {
    int u = (t < 128 && t >= off) ? sums[t - off] : 0;
    __syncthreads();
    if (t < 128) sums[t] += u;
    __syncthreads();
  }
  if (t < 128) dh[128 + t] = sums[t] - dv;
  __syncthreads();
  if (t < nd) {
    int pos = d0 + atomicAdd(&dh[128 + c], 1);
    sbeg[pos] = rbeg + lbase; send[pos] = rbeg + lbase + h;
    sdinv[pos] = di; sdn[pos] = d0 + t;
  }
  __syncthreads();

  // build permutation in LDS (random LDS ushort writes: cheap)
  for (int i = t; i < cnt; i += 1024) {
    unsigned pk = lbuf[i];
    int q = atomicAdd(&cur8[(int)(pk >> 17) * NRG + (int)((pk & 0x1FFFF) >> RG_SHIFT)], 1);
    perm[q] = (unsigned short)i;
  }
  __syncthreads();

  // linear coalesced csr write-out
  for (int pos = t; pos < cnt; pos += 1024)
    csr[rbeg + pos] = (int)(lbuf[perm[pos]] & 0x1FFFF);
}

// ---------------- combined misc prep: init bcur, weight transposes ----------------

__global__ __launch_bounds__(256) void prep_misc_kernel(
    const float* __restrict__ lin1_w, const float* __restrict__ gcn_w,
    const float* __restrict__ lin2_w, int* __restrict__ bcur,
    unsigned short* __restrict__ Wt, unsigned short* __restrict__ W2t) {
  int b = blockIdx.x;
  int t = threadIdx.x;
  if (b == 0) {
    if (t < NBUCK) bcur[t] = t * BCAP;
  } else if (b <= 32) {
    int m = (b - 1) >> 3;        // which 128x128 matrix (0..3)
    int chunk = (b - 1) & 7;     // which eighth of it
    const float* src = (m == 0) ? lin1_w : (gcn_w + (size_t)(m - 1) * 16384);
    unsigned short* dstp = Wt + (size_t)m * 16384;
    int i0 = chunk * 2048;
    for (int i = i0 + t; i < i0 + 2048; i += 256) {
      int n = i >> 7, k = i & 127;
      dstp[(size_t)n * 128 + k] = bf16r(src[(size_t)k * 128 + n]);
    }
  } else {
    int chunk = b - 33;          // 0..1
    int i0 = chunk * 3072;
    for (int i = i0 + t; i < i0 + 3072; i += 256) {
      int n = i >> 7, k = i & 127;
      W2t[i] = (n < OUTC) ? bf16r(lin2_w[(size_t)k * OUTC + n]) : (unsigned short)0;
    }
  }
}

// ---------------- MFMA GEMM (operand-swapped epilogue) ----------------
// MODE 0: A bf16 -> Y16 = relu(acc+bias); MODE 1: A bf16 -> Y8 = fp8(dinv*acc);
// MODE 2: A fp32 (in-flight bf16 cvt) -> Y16 = relu(acc+bias).

template <int MODE>
__global__ __launch_bounds__(256) void gemm_mfma_kernel(
    const void* __restrict__ Av, const unsigned short* __restrict__ Wt,
    const float* __restrict__ bias, const float* __restrict__ dinv,
    void* __restrict__ Y, int M) {
  int t = threadIdx.x;
  int w = t >> 6;
  int l = t & 63;
  int quad = l >> 4;
  int m16 = l & 15;
  int row0 = blockIdx.x * 64;
  int colbase = w * 32;

  floatx4 acc[4][2];
#pragma unroll
  for (int rt = 0; rt < 4; rt++)
#pragma unroll
    for (int ct = 0; ct < 2; ct++) acc[rt][ct] = (floatx4)0.f;

#pragma unroll
  for (int kc = 0; kc < 4; kc++) {
    int kof = kc * 32 + quad * 8;
    short8 a0 = *(const short8*)(Wt + (size_t)(colbase + m16) * 128 + kof);
    short8 a1 = *(const short8*)(Wt + (size_t)(colbase + 16 + m16) * 128 + kof);
#pragma unroll
    for (int rt = 0; rt < 4; rt++) {
      short8 bfr;
      if (MODE == 2) {
        const float* Af = (const float*)Av + (size_t)(row0 + rt * 16 + m16) * 128 + kof;
        float4 f0 = *(const float4*)Af;
        float4 f1 = *(const float4*)(Af + 4);
        unsigned u0 = pack_bf16x2(f0.x, f0.y);
        unsigned u1 = pack_bf16x2(f0.z, f0.w);
        unsigned u2 = pack_bf16x2(f1.x, f1.y);
        unsigned u3 = pack_bf16x2(f1.z, f1.w);
        bfr[0] = (short)(u0 & 0xFFFF); bfr[1] = (short)(u0 >> 16);
        bfr[2] = (short)(u1 & 0xFFFF); bfr[3] = (short)(u1 >> 16);
        bfr[4] = (short)(u2 & 0xFFFF); bfr[5] = (short)(u2 >> 16);
        bfr[6] = (short)(u3 & 0xFFFF); bfr[7] = (short)(u3 >> 16);
      } else {
        bfr = *(const short8*)((const unsigned short*)Av +
                               (size_t)(row0 + rt * 16 + m16) * 128 + kof);
      }
      acc[rt][0] = __builtin_amdgcn_mfma_f32_16x16x32_bf16(a0, bfr, acc[rt][0], 0, 0, 0);
      acc[rt][1] = __builtin_amdgcn_mfma_f32_16x16x32_bf16(a1, bfr, acc[rt][1], 0, 0, 0);
    }
  }

  if (MODE != 1) {
    unsigned short* Y16 = (unsigned short*)Y;
    float4 bv0 = *(const float4*)(bias + colbase + quad * 4);
    float4 bv1 = *(const float4*)(bias + colbase + 16 + quad * 4);
#pragma unroll
    for (int rt = 0; rt < 4; rt++) {
      int row = row0 + rt * 16 + m16;
      if (row < M) {
        uint2 s0, s1;
        s0.x = pack_bf16x2(fmaxf(acc[rt][0][0] + bv0.x, 0.f),
                           fmaxf(acc[rt][0][1] + bv0.y, 0.f));
        s0.y = pack_bf16x2(fmaxf(acc[rt][0][2] + bv0.z, 0.f),
                           fmaxf(acc[rt][0][3] + bv0.w, 0.f));
        s1.x = pack_bf16x2(fmaxf(acc[rt][1][0] + bv1.x, 0.f),
                           fmaxf(acc[rt][1][1] + bv1.y, 0.f));
        s1.y = pack_bf16x2(fmaxf(acc[rt][1][2] + bv1.z, 0.f),
                           fmaxf(acc[rt][1][3] + bv1.w, 0.f));
        *(uint2*)(Y16 + (size_t)row * 128 + colbase + quad * 4) = s0;
        *(uint2*)(Y16 + (size_t)row * 128 + colbase + 16 + quad * 4) = s1;
      }
    }
  } else {
    unsigned* Y8 = (unsigned*)Y;  // 32 uints per row
#pragma unroll
    for (int rt = 0; rt < 4; rt++) {
      int row = row0 + rt * 16 + m16;
      if (row < M) {
        float dd = dinv[row];
        unsigned u0 = 0, u1 = 0;
        u0 = __builtin_amdgcn_cvt_pk_fp8_f32(acc[rt][0][0] * dd, acc[rt][0][1] * dd, (int)u0, false);
        u0 = __builtin_amdgcn_cvt_pk_fp8_f32(acc[rt][0][2] * dd, acc[rt][0][3] * dd, (int)u0, true);
        u1 = __builtin_amdgcn_cvt_pk_fp8_f32(acc[rt][1][0] * dd, acc[rt][1][1] * dd, (int)u1, false);
        u1 = __builtin_amdgcn_cvt_pk_fp8_f32(acc[rt][1][2] * dd, acc[rt][1][3] * dd, (int)u1, true);
        Y8[(size_t)row * 32 + (colbase >> 2) + quad] = u0;
        Y8[(size_t)row * 32 + ((colbase + 16) >> 2) + quad] = u1;
      }
    }
  }
}

// ---------------- aggregation: 8 lanes own one node, sorted metadata ----------------
// R7 band-major remap + R6 range-ordered csr + unroll-8 + nt stores (unchanged).

#define ACC8(u)                                                       \
  acc[0] += __builtin_amdgcn_cvt_pk_f32_fp8((int)(u).x, false);       \
  acc[1] += __builtin_amdgcn_cvt_pk_f32_fp8((int)(u).x, true);        \
  acc[2] += __builtin_amdgcn_cvt_pk_f32_fp8((int)(u).y, false);       \
  acc[3] += __builtin_amdgcn_cvt_pk_f32_fp8((int)(u).y, true);        \
  acc[4] += __builtin_amdgcn_cvt_pk_f32_fp8((int)(u).z, false);       \
  acc[5] += __builtin_amdgcn_cvt_pk_f32_fp8((int)(u).z, true);        \
  acc[6] += __builtin_amdgcn_cvt_pk_f32_fp8((int)(u).w, false);       \
  acc[7] += __builtin_amdgcn_cvt_pk_f32_fp8((int)(u).w, true);

__global__ __launch_bounds__(256) void aggregate_fp8_kernel(
    const uint4* __restrict__ Ht8, const int* __restrict__ csr,
    const int* __restrict__ sbeg, const int* __restrict__ send,
    const float* __restrict__ sdinv, const int* __restrict__ sdn,
    const float* __restrict__ bias, uint4* __restrict__ Out, int N) {
  int wid = (blockIdx.x * blockDim.x + threadIdx.x) >> 6;
  int lane = threadIdx.x & 63;
  int g = lane >> 3;
  int c8 = lane & 7;
  int bucket = wid % NBUCK;
  int band = wid / NBUCK;          // 0..63
  int idx = (bucket << 9) + (band << 3) + g;
  if (idx >= N) return;
  int beg = sbeg[idx], end = send[idx];
  int d = sdn[idx];

  floatx2 acc[8];
  {
    uint4 us = Ht8[(size_t)d * 8 + c8];
    acc[0] = __builtin_amdgcn_cvt_pk_f32_fp8((int)us.x, false);
    acc[1] = __builtin_amdgcn_cvt_pk_f32_fp8((int)us.x, true);
    acc[2] = __builtin_amdgcn_cvt_pk_f32_fp8((int)us.y, false);
    acc[3] = __builtin_amdgcn_cvt_pk_f32_fp8((int)us.y, true);
    acc[4] = __builtin_amdgcn_cvt_pk_f32_fp8((int)us.z, false);
    acc[5] = __builtin_amdgcn_cvt_pk_f32_fp8((int)us.z, true);
    acc[6] = __builtin_amdgcn_cvt_pk_f32_fp8((int)us.w, false);
    acc[7] = __builtin_amdgcn_cvt_pk_f32_fp8((int)us.w, true);
  }
  int i = beg;
  int s0, s1, s2, s3, s4, s5, s6, s7;
  if (i + 7 < end) {
    s0 = csr[i];     s1 = csr[i + 1]; s2 = csr[i + 2]; s3 = csr[i + 3];
    s4 = csr[i + 4]; s5 = csr[i + 5]; s6 = csr[i + 6]; s7 = csr[i + 7];
  }
  while (i + 7 < end) {
    uint4 u0 = Ht8[(size_t)s0 * 8 + c8];
    uint4 u1 = Ht8[(size_t)s1 * 8 + c8];
    uint4 u2 = Ht8[(size_t)s2 * 8 + c8];
    uint4 u3 = Ht8[(size_t)s3 * 8 + c8];
    uint4 u4 = Ht8[(size_t)s4 * 8 + c8];
    uint4 u5 = Ht8[(size_t)s5 * 8 + c8];
    uint4 u6 = Ht8[(size_t)s6 * 8 + c8];
    uint4 u7 = Ht8[(size_t)s7 * 8 + c8];
    i += 8;
    if (i + 7 < end) {
      s0 = csr[i];     s1 = csr[i + 1]; s2 = csr[i + 2]; s3 = csr[i + 3];
      s4 = csr[i + 4]; s5 = csr[i + 5]; s6 = csr[i + 6]; s7 = csr[i + 7];
    }
    ACC8(u0) ACC8(u1) ACC8(u2) ACC8(u3) ACC8(u4) ACC8(u5) ACC8(u6) ACC8(u7)
  }
  if (i + 3 < end) {
    int t0 = csr[i], t1 = csr[i + 1], t2 = csr[i + 2], t3 = csr[i + 3];
    uint4 u0 = Ht8[(size_t)t0 * 8 + c8];
    uint4 u1 = Ht8[(size_t)t1 * 8 + c8];
    uint4 u2 = Ht8[(size_t)t2 * 8 + c8];
    uint4 u3 = Ht8[(size_t)t3 * 8 + c8];
    ACC8(u0) ACC8(u1) ACC8(u2) ACC8(u3)
    i += 4;
  }
  for (; i < end; ++i) {
    uint4 u0 = Ht8[(size_t)csr[i] * 8 + c8];
    ACC8(u0)
  }

  float dd = sdinv[idx];
  const float4* b4 = (const float4*)bias;
  float4 bv0 = b4[4 * c8 + 0];
  float4 bv1 = b4[4 * c8 + 1];
  float4 bv2 = b4[4 * c8 + 2];
  float4 bv3 = b4[4 * c8 + 3];
  uintx4 o0, o1;
  o0.x = pack_bf16x2(fmaxf(fmaf(dd, acc[0][0], bv0.x), 0.f),
                     fmaxf(fmaf(dd, acc[0][1], bv0.y), 0.f));
  o0.y = pack_bf16x2(fmaxf(fmaf(dd, acc[1][0], bv0.z), 0.f),
                     fmaxf(fmaf(dd, acc[1][1], bv0.w), 0.f));
  o0.z = pack_bf16x2(fmaxf(fmaf(dd, acc[2][0], bv1.x), 0.f),
                     fmaxf(fmaf(dd, acc[2][1], bv1.y), 0.f));
  o0.w = pack_bf16x2(fmaxf(fmaf(dd, acc[3][0], bv1.z), 0.f),
                     fmaxf(fmaf(dd, acc[3][1], bv1.w), 0.f));
  o1.x = pack_bf16x2(fmaxf(fmaf(dd, acc[4][0], bv2.x), 0.f),
                     fmaxf(fmaf(dd, acc[4][1], bv2.y), 0.f));
  o1.y = pack_bf16x2(fmaxf(fmaf(dd, acc[5][0], bv2.z), 0.f),
                     fmaxf(fmaf(dd, acc[5][1], bv2.w), 0.f));
  o1.z = pack_bf16x2(fmaxf(fmaf(dd, acc[6][0], bv3.x), 0.f),
                     fmaxf(fmaf(dd, acc[6][1], bv3.y), 0.f));
  o1.w = pack_bf16x2(fmaxf(fmaf(dd, acc[7][0], bv3.z), 0.f),
                     fmaxf(fmaf(dd, acc[7][1], bv3.w), 0.f));
  __builtin_nontemporal_store(o0, (uintx4*)(Out + (size_t)d * 16 + 2 * c8));
  __builtin_nontemporal_store(o1, (uintx4*)(Out + (size_t)d * 16 + 2 * c8 + 1));
}

// ---------------- head: MFMA logits + LDS log_softmax ----------------

__global__ __launch_bounds__(256) void head_mfma_kernel(
    const unsigned short* __restrict__ A, const unsigned short* __restrict__ W2t,
    const float* __restrict__ b2, float* __restrict__ Out, int N) {
  __shared__ float lg[64][48];
  __shared__ float bs[48];
  int t = threadIdx.x;
  int w = t >> 6, l = t & 63, quad = l >> 4, m16 = l & 15;
  if (t < 48) bs[t] = (t < OUTC) ? b2[t] : 0.f;
  int row0 = blockIdx.x * 64;

  floatx4 acc[3];
  acc[0] = (floatx4)0.f; acc[1] = (floatx4)0.f; acc[2] = (floatx4)0.f;
  const unsigned short* Aw = A + (size_t)(row0 + w * 16) * 128;
#pragma unroll
  for (int kc = 0; kc < 4; kc++) {
    int kof = kc * 32 + quad * 8;
    short8 a = *(const short8*)(Aw + (size_t)m16 * 128 + kof);
#pragma unroll
    for (int ct = 0; ct < 3; ct++) {
      short8 b = *(const short8*)(W2t + (size_t)(ct * 16 + m16) * 128 + kof);
      acc[ct] = __builtin_amdgcn_mfma_f32_16x16x32_bf16(a, b, acc[ct], 0, 0, 0);
    }
  }
#pragma unroll
  for (int ct = 0; ct < 3; ct++)
#pragma unroll
    for (int j = 0; j < 4; j++)
      lg[w * 16 + quad * 4 + j][ct * 16 + m16] = acc[ct][j];
  __syncthreads();

  int r = t >> 2, sub = t & 3;
  int row = row0 + r;
  float vals[10];
  float mx = -3.4e38f;
#pragma unroll
  for (int j = 0; j < 10; j++) {
    float v = lg[r][sub * 10 + j] + bs[sub * 10 + j];
    vals[j] = v;
    mx = fmaxf(mx, v);
  }
  mx = fmaxf(mx, __shfl_xor(mx, 1, 64));
  mx = fmaxf(mx, __shfl_xor(mx, 2, 64));
  float se = 0.f;
#pragma unroll
  for (int j = 0; j < 10; j++) se += expf(vals[j] - mx);
  se += __shfl_xor(se, 1, 64);
  se += __shfl_xor(se, 2, 64);
  if (row < N) {
    float ls = logf(se);
#pragma unroll
    for (int j = 0; j < 10; j++)
      Out[(size_t)row * OUTC + sub * 10 + j] = vals[j] - mx - ls;
  }
}

// ---------------- launch ----------------

extern "C" void kernel_launch(void* const* d_in, const int* in_sizes, int n_in,
                              void* d_out, int out_size, void* d_ws, size_t ws_size,
                              hipStream_t stream) {
  const float* x      = (const float*)d_in[0];
  const int*   edge   = (const int*)d_in[1];
  const float* lin1_w = (const float*)d_in[2];
  const float* lin1_b = (const float*)d_in[3];
  const float* gcn_w  = (const float*)d_in[4];
  const float* gcn_b  = (const float*)d_in[5];
  const float* lin2_w = (const float*)d_in[6];
  const float* lin2_b = (const float*)d_in[7];
  float* out = (float*)d_out;

  const int N = NN;
  const int E = in_sizes[1] / 2;  // 3,200,000
  const int* src = edge;
  const int* dst = edge + E;

  char* p = (char*)d_ws;
  auto alloc = [&](size_t bytes) { char* q = p; p += (bytes + 255) & ~(size_t)255; return q; };
  unsigned*       hA16    = (unsigned*)alloc((size_t)NP * 128 * 2);          // 25.6 MB
  unsigned*       hB8     = (unsigned*)alloc((size_t)NP * 32 * 4);           // 12.8 MB
  unsigned*       pairs   = (unsigned*)alloc((size_t)NBUCK * BCAP * 4);      // 14.4 MB
  int*            csr     = (int*)alloc((size_t)NBUCK * BCAP * 4);           // 14.4 MB
  float*          dinv    = (float*)alloc((size_t)NP * 4);
  int*            sbeg    = (int*)alloc((size_t)N * 4);
  int*            send    = (int*)alloc((size_t)N * 4);
  float*          sdinv   = (float*)alloc((size_t)N * 4);
  int*            sdn     = (int*)alloc((size_t)N * 4);
  unsigned short* Wt      = (unsigned short*)alloc((size_t)4 * 16384 * 2);
  unsigned short* W2t     = (unsigned short*)alloc((size_t)48 * 128 * 2);
  int*            bcur    = (int*)alloc(256 * 4);

  // prep: bcur init + weight transposes (one dispatch), then partition + fill
  prep_misc_kernel<<<35, 256, 0, stream>>>(lin1_w, gcn_w, lin2_w, bcur, Wt, W2t);
  partition_kernel<<<(E + PT_TILE - 1) / PT_TILE, 512, 0, stream>>>(src, dst, bcur, pairs, E);
  bucket_fill_kernel<<<NBUCK, 1024, 0, stream>>>(pairs, bcur, dinv, csr,
                                                 sbeg, send, sdinv, sdn, N);

  int gb = NP / 64;  // 1563
  gemm_mfma_kernel<2><<<gb, 256, 0, stream>>>((const void*)x, Wt,
                                              lin1_b, nullptr, (void*)hA16, N);
  int ablocks = (NBUCK * 64) / 4;  // 3136 blocks: band-major wave space (196x64)
  for (int k = 0; k < 3; k++) {
    gemm_mfma_kernel<1><<<gb, 256, 0, stream>>>((const void*)hA16,
                                                Wt + (size_t)(k + 1) * 16384,
                                                nullptr, dinv, (void*)hB8, N);
    aggregate_fp8_kernel<<<ablocks, 256, 0, stream>>>(
        (const uint4*)hB8, csr, sbeg, send, sdinv, sdn, gcn_b + (size_t)k * 128,
        (uint4*)hA16, N);
  }
  head_mfma_kernel<<<gb, 256, 0, stream>>>((const unsigned short*)hA16, W2t,
                                           lin2_b, out, N);
}